// Round 6
// baseline (983.528 us; speedup 1.0000x reference)
//
#include <hip/hip_runtime.h>
#include <hip/hip_bf16.h>

// UCCAEncoder: 3x EdgeConv(max) + FFN + gather. R15:
//  - edge kernel: SINGLE-BARRIER phases. Bs triple-buffered (3x16KB chunks,
//    Bk=32), As double-buffered (2x8KB) -> the end-of-phase barrier (write-
//    after-read guard) is provably unnecessary: chunk h+2 is staged AFTER
//    barrier(h), and all waves' phase h-1 reads completed (lgkmcnt(0) before
//    their MFMAs) before any wave passed barrier(h). 17 barriers/block vs 33.
//    Waves may skew across phases -> LDS-read bursts overlap MFMA instead of
//    serializing post-barrier (the measured ~45% dead time in R12-R14).
//  - counted vmcnt (FIFO sim, A-first prologue): steady vmcnt(8), tail 4/4/0.
//    zpack's implicit wait drains only its A loads (B stays in flight).
//  - shape: 64e x 256c, 256 thr, 4 waves, 8192 blocks, LDS 64KB -> 2 blocks/CU
//    (co-tenancy hides prologue/epilogue; 4-wave barrier groups).
//  - keeps: LDS key-tile epilogue w/ interior plain stores (R13), sorted edges,
//    XCD swizzle (n-half pairs same XCD), fused U/V node GEMM, fp16 z path.

#define N_NODES 16384
#define EDGES   262144
#define HDIM    512
#define SEQ     2048

typedef __attribute__((ext_vector_type(8))) short short8;
typedef __attribute__((ext_vector_type(8))) _Float16 half8;
typedef __attribute__((ext_vector_type(2))) _Float16 half2v;
typedef __attribute__((ext_vector_type(4))) float f32x4;

__device__ __forceinline__ void gld16(const void* g, void* l) {
    __builtin_amdgcn_global_load_lds(
        (const __attribute__((address_space(1))) void*)g,
        (__attribute__((address_space(3))) void*)l, 16, 0, 0);
}
__device__ __forceinline__ unsigned short f2b(float f) {   // fp32 -> bf16 RNE
    unsigned int x = __float_as_uint(f);
    return (unsigned short)((x + 0x7fffu + ((x >> 16) & 1u)) >> 16);
}
__device__ __forceinline__ unsigned short f2h(float f) {   // fp32 -> fp16 bits
    _Float16 h = (_Float16)f;
    return __builtin_bit_cast(unsigned short, h);
}
// packed fp16: z = max(u+v, 0) (v_pk_add_f16 + v_pk_max_f16)
__device__ __forceinline__ unsigned int zpack_h(unsigned int u, unsigned int v) {
    half2v a = __builtin_bit_cast(half2v, u);
    half2v b = __builtin_bit_cast(half2v, v);
    half2v s = a + b;
    half2v z = {(_Float16)0.f, (_Float16)0.f};
    half2v r = __builtin_elementwise_max(s, z);
    return __builtin_bit_cast(unsigned int, r);
}
// ---- Bk=32 LDS swizzle (node/FFN GEMMs): slot = seg ^ ((row>>1)&3), row stride 64B
__device__ __forceinline__ short8 frag_ld(const short* S, int row, int q) {
    int p = q ^ ((row >> 1) & 3);
    return *(const short8*)(S + row * 32 + p * 8);
}
__device__ __forceinline__ void stage_tile(const short* G, int kc, short* S, int t) {
#pragma unroll
    for (int it = 0; it < 2; ++it) {
        int lin = it * 256 + t;
        int row = lin >> 2, p = lin & 3;
        int q = p ^ ((row >> 1) & 3);
        gld16(G + (size_t)row * HDIM + kc + q * 8, S + lin * 8);
    }
}
__device__ __forceinline__ void mfma_tile_bf16(const short* As, const short* Bs,
                                               int wm, int wn, int l, f32x4 acc[4][4]) {
    short8 a[4], b[4];
#pragma unroll
    for (int mt = 0; mt < 4; ++mt) a[mt] = frag_ld(As, wm + mt * 16 + (l & 15), l >> 4);
#pragma unroll
    for (int nt = 0; nt < 4; ++nt) b[nt] = frag_ld(Bs, wn + nt * 16 + (l & 15), l >> 4);
#pragma unroll
    for (int mt = 0; mt < 4; ++mt)
#pragma unroll
        for (int nt = 0; nt < 4; ++nt)
            acc[mt][nt] = __builtin_amdgcn_mfma_f32_16x16x32_bf16(a[mt], b[nt], acc[mt][nt], 0, 0, 0);
}
// ---- Bk=64 LDS swizzle (edge A tile): row stride 128B = bank wrap ->
//      slot = seg ^ ((row>>1)&7) ^ (row&1); 8 segs of 8 els per row.
__device__ __forceinline__ half8 frag64(const short* S, int row, int q) {
    int p = q ^ ((row >> 1) & 7) ^ (row & 1);
    return *(const half8*)(S + row * 64 + p * 8);
}
// ---- Bk=32 B-chunk staging (edge kernel, 256 thr): 256 rows x 32 els
__device__ __forceinline__ void stageB32(const short* __restrict__ Wt, int n0, int col0,
                                         short* buf, int t) {
#pragma unroll
    for (int it = 0; it < 4; ++it) {
        int lin = it * 256 + t;
        int row = lin >> 2, s = lin & 3;
        int q = s ^ ((row >> 1) & 3);
        gld16(Wt + (size_t)(n0 + row) * HDIM + col0 + q * 8, buf + lin * 8);
    }
}

// ================= edge sort (counting sort by dst) =================
__global__ __launch_bounds__(256) void hist_kernel(
    const int* __restrict__ dst, int* __restrict__ hist) {
    int idx = blockIdx.x * 256 + threadIdx.x;
    atomicAdd(&hist[dst[idx]], 1);
}
__global__ __launch_bounds__(256) void scan_kernel(
    const int* __restrict__ hist, int* __restrict__ cursor) {
    __shared__ int part[256];
    const int t = threadIdx.x, base = t * 64;
    int sum = 0;
    for (int i = 0; i < 64; ++i) sum += hist[base + i];
    part[t] = sum;
    __syncthreads();
    int run = 0;
    for (int i = 0; i < t; ++i) run += part[i];
    for (int i = 0; i < 64; ++i) {
        int h = hist[base + i];
        cursor[base + i] = run;
        run += h;
    }
}
__global__ __launch_bounds__(256) void scatter_kernel(
    const int* __restrict__ dst, const int* __restrict__ src,
    int* __restrict__ cursor, int* __restrict__ dstS, int* __restrict__ srcS) {
    int idx = blockIdx.x * 256 + threadIdx.x;
    int d = dst[idx];
    int p = atomicAdd(&cursor[d], 1);
    dstS[p] = d;
    srcS[p] = src[idx];
}

// ================= weights / input prep =================
// conv trio -> [n][k]: z=0 Wd=w1a-w1b (bf16), z=1 w1b (bf16), z=2 w2 (fp16)
__global__ __launch_bounds__(256) void prep_weights_kernel(
    const float* __restrict__ w1, const float* __restrict__ w2,
    short* __restrict__ WdT, short* __restrict__ w1bT, short* __restrict__ W2T) {
    __shared__ float tile[32][33];
    const int which = blockIdx.z;
    const int k0 = blockIdx.x * 32, n0 = blockIdx.y * 32;
    const int tx = threadIdx.x, ty = threadIdx.y;
#pragma unroll
    for (int i = 0; i < 4; ++i) {
        int k = k0 + ty + i * 8, n = n0 + tx;
        float v;
        if (which == 0)      v = w1[k * 512 + n] - w1[(k + 512) * 512 + n];
        else if (which == 1) v = w1[(k + 512) * 512 + n];
        else                 v = w2[k * 512 + n];
        tile[ty + i * 8][tx] = v;
    }
    __syncthreads();
    short* out = which == 0 ? WdT : (which == 1 ? w1bT : W2T);
#pragma unroll
    for (int i = 0; i < 4; ++i) {
        int n = n0 + ty + i * 8, k = k0 + tx;
        float v = tile[tx][ty + i * 8];
        out[(size_t)n * 512 + k] = (short)(which == 2 ? f2h(v) : f2b(v));
    }
}
// FFN mats (bf16): z=0 fw1, z=1 fw2
__global__ __launch_bounds__(256) void tr_kernel(
    const float* __restrict__ W1, const float* __restrict__ W2,
    short* __restrict__ T1, short* __restrict__ T2) {
    __shared__ float tile[32][33];
    const float* W = blockIdx.z ? W2 : W1;
    short* T = blockIdx.z ? T2 : T1;
    const int k0 = blockIdx.x * 32, n0 = blockIdx.y * 32;
    const int tx = threadIdx.x, ty = threadIdx.y;
#pragma unroll
    for (int i = 0; i < 4; ++i)
        tile[ty + i * 8][tx] = W[(k0 + ty + i * 8) * 512 + n0 + tx];
    __syncthreads();
#pragma unroll
    for (int i = 0; i < 4; ++i)
        T[(size_t)(n0 + ty + i * 8) * 512 + k0 + tx] = (short)f2b(tile[tx][ty + i * 8]);
}
__global__ __launch_bounds__(256) void cvt_bf16_kernel(
    const float* __restrict__ x, short* __restrict__ xb) {
    int idx = blockIdx.x * 256 + threadIdx.x;
    float4 v = ((const float4*)x)[idx];
    uint2 o;
    o.x = (unsigned int)f2b(v.x) | ((unsigned int)f2b(v.y) << 16);
    o.y = (unsigned int)f2b(v.z) | ((unsigned int)f2b(v.w) << 16);
    ((uint2*)xb)[idx] = o;
}

// ================= fused U/V node GEMM (bf16 in, fp16 out) =================
// grid (128, 8): y<4 -> U = h@WdT^T + b1 ; y>=4 -> V = h@w1bT^T
__global__ __launch_bounds__(256) void node_gemm_uv_kernel(
    const short* __restrict__ A, const short* __restrict__ WdT,
    const short* __restrict__ w1bT, const float* __restrict__ b1,
    short* __restrict__ U, short* __restrict__ V) {
    __shared__ short As[128 * 32];
    __shared__ short Bs[128 * 32];
    const int t = threadIdx.x;
    const int by = blockIdx.y;
    const short* Wt = (by < 4) ? WdT : w1bT;
    short* C = (by < 4) ? U : V;
    const float* bias = (by < 4) ? b1 : nullptr;
    const int m0 = blockIdx.x * 128, n0 = (by & 3) * 128;
    const int w = t >> 6, l = t & 63;
    const int wm = (w & 1) * 64, wn = (w >> 1) * 64;
    f32x4 acc[4][4] = {};
    for (int kc = 0; kc < HDIM; kc += 32) {
        stage_tile(A + (size_t)m0 * HDIM, kc, As, t);
        stage_tile(Wt + (size_t)n0 * HDIM, kc, Bs, t);
        __syncthreads();
        mfma_tile_bf16(As, Bs, wm, wn, l, acc);
        __syncthreads();
    }
#pragma unroll
    for (int mt = 0; mt < 4; ++mt) {
        int m = m0 + wm + mt * 16 + (l >> 4) * 4;
#pragma unroll
        for (int nt = 0; nt < 4; ++nt) {
            int n = n0 + wn + nt * 16 + (l & 15);
            float bv = bias ? bias[n] : 0.f;
#pragma unroll
            for (int r = 0; r < 4; ++r)
                C[(size_t)(m + r) * HDIM + n] = (short)f2h(acc[mt][nt][r] + bv);
        }
    }
}

// ====== edge GEMM (sorted, fp16, 64e x 256n, single-barrier 3-buf pipeline) ======
__device__ __forceinline__ unsigned int fkey(float m) {    // monotone fp32->uint
    unsigned int b = __float_as_uint(m);
    return ((int)b < 0) ? ~b : (b | 0x80000000u);
}
__device__ __forceinline__ void kflush(unsigned int* K, int d, int col, float m) {
    atomicMax(K + (((size_t)d) << 9) + col, fkey(m));
}
__global__ __launch_bounds__(256, 2) void edge_mfma_kernel(
    const short* __restrict__ U, const short* __restrict__ V,
    const short* __restrict__ Wt, const int* __restrict__ srcS,
    const int* __restrict__ dstS, unsigned int* __restrict__ K) {
    __shared__ short As[2][64 * 64];      // 16 KB: z tiles (fp16, 64 wide), dbuf
    __shared__ short Bs[3][256 * 32];     // 48 KB: W2^T chunks (fp16, Bk=32), 3-buf
    // total 64 KB -> 2 blocks/CU
    const int t = threadIdx.x;
    // XCD swizzle: L%8 = XCD; the 2 n-halves of edge-group g are 8 apart.
    const int L  = blockIdx.x;                 // 0..8191
    const int g  = (L >> 4) * 8 + (L & 7);     // edge-group 0..4095 (64 edges)
    const int nh = (L >> 3) & 1;               // n-half
    const int e0 = g * 64, n0 = nh * 256;
    const int w = t >> 6, l = t & 63;
    const int wnb = w * 64;                    // 64-col slice
    const int lm = l & 15;
    const int arow = t >> 2, s0 = (t & 3) * 2; // thread covers 32B (segs s0,s0+1)
    const int perm = ((arow >> 1) & 7) ^ (arow & 1);
    const int p0 = s0 ^ perm, p1 = (s0 + 1) ^ perm;
    const int drow = dstS[e0 + arow];          // L2-hot
    const int srow = srcS[e0 + arow];
    const short* up = U + (((size_t)drow) << 9) + s0 * 8;
    const short* vp = V + (((size_t)srow) << 9) + s0 * 8;
    f32x4 acc[4][4] = {};
    uint4 pu0, pu1, pv0, pv1;
    // ---- prologue (vm FIFO: A(0):4, B0:4, B1:4 -> zpack drains A(0) only) ----
    pu0 = *(const uint4*)(up);      pu1 = *(const uint4*)(up + 8);
    pv0 = *(const uint4*)(vp);      pv1 = *(const uint4*)(vp + 8);
    stageB32(Wt, n0, 0,  Bs[0], t);
    stageB32(Wt, n0, 32, Bs[1], t);
    {
        uint4 z0, z1;
        z0.x = zpack_h(pu0.x, pv0.x); z0.y = zpack_h(pu0.y, pv0.y);
        z0.z = zpack_h(pu0.z, pv0.z); z0.w = zpack_h(pu0.w, pv0.w);
        z1.x = zpack_h(pu1.x, pv1.x); z1.y = zpack_h(pu1.y, pv1.y);
        z1.z = zpack_h(pu1.z, pv1.z); z1.w = zpack_h(pu1.w, pv1.w);
        unsigned int* du = (unsigned int*)As[0];
        *(uint4*)(du + arow * 32 + p0 * 4) = z0;
        *(uint4*)(du + arow * 32 + p1 * 4) = z1;
    }
    pu0 = *(const uint4*)(up + 64); pu1 = *(const uint4*)(up + 64 + 8);   // A(1)
    pv0 = *(const uint4*)(vp + 64); pv1 = *(const uint4*)(vp + 64 + 8);
    // ---- 16 phases, ONE barrier each. Phase h: cols [h*32, h*32+32) from
    // Bs[h%3], A segs half (h&1) of As[(h>>1)&1].
    // vm FIFO at the wait of phase h: steady outstanding = B(h):4 + 8 younger
    // -> vmcnt(8); h=13/14: vmcnt(4); h=15: vmcnt(0). zpack's implicit wait in
    // phase 2j drains A(j+1) (and older) only -- B(2j+1),B(2j+2) stay in flight.
    // Safety w/o end barrier: stage of B(h+2) & As writes happen AFTER
    // barrier(h); all waves' phase h-1 reads completed (lgkmcnt(0) pre-MFMA)
    // before any wave passed barrier(h). 3-buf B / 2-buf As make the target
    // buffer's last readers exactly phase h-1 (or older).
#pragma unroll
    for (int h = 0; h < 16; ++h) {
        if (h <= 12)       asm volatile("s_waitcnt vmcnt(8) lgkmcnt(0)" ::: "memory");
        else if (h <= 14)  asm volatile("s_waitcnt vmcnt(4) lgkmcnt(0)" ::: "memory");
        else               asm volatile("s_waitcnt vmcnt(0) lgkmcnt(0)" ::: "memory");
        __builtin_amdgcn_s_barrier();
        asm volatile("" ::: "memory");
        if (h < 14)
            stageB32(Wt, n0, (h + 2) * 32, Bs[(h + 2) % 3], t);
        if ((h & 1) == 0) {
            const int j = h >> 1;
            if (j <= 6) {                       // zpack tile j+1 -> As[(j+1)&1]
                uint4 z0, z1;
                z0.x = zpack_h(pu0.x, pv0.x); z0.y = zpack_h(pu0.y, pv0.y);
                z0.z = zpack_h(pu0.z, pv0.z); z0.w = zpack_h(pu0.w, pv0.w);
                z1.x = zpack_h(pu1.x, pv1.x); z1.y = zpack_h(pu1.y, pv1.y);
                z1.z = zpack_h(pu1.z, pv1.z); z1.w = zpack_h(pu1.w, pv1.w);
                unsigned int* du = (unsigned int*)As[(j + 1) & 1];
                *(uint4*)(du + arow * 32 + p0 * 4) = z0;
                *(uint4*)(du + arow * 32 + p1 * 4) = z1;
                if (j <= 5) {                   // reload A(j+2) into same regs
                    const int kn = (j + 2) * 64;
                    pu0 = *(const uint4*)(up + kn); pu1 = *(const uint4*)(up + kn + 8);
                    pv0 = *(const uint4*)(vp + kn); pv1 = *(const uint4*)(vp + kn + 8);
                }
            }
        }
        const short* Ab = As[(h >> 1) & 1];
        const short* Bb = Bs[h % 3];
        const int hq = (h & 1) * 4 + (l >> 4);
        __builtin_amdgcn_s_setprio(1);
        half8 b[4];
#pragma unroll
        for (int nt = 0; nt < 4; ++nt) {
            int row = wnb + nt * 16 + lm;
            int p = (l >> 4) ^ ((row >> 1) & 3);
            b[nt] = *(const half8*)(Bb + row * 32 + p * 8);
        }
#pragma unroll
        for (int mt = 0; mt < 4; ++mt) {
            half8 a = frag64(Ab, mt * 16 + lm, hq);
#pragma unroll
            for (int nt = 0; nt < 4; ++nt)
                acc[mt][nt] = __builtin_amdgcn_mfma_f32_16x16x32_f16(a, b[nt], acc[mt][nt], 0, 0, 0);
        }
        __builtin_amdgcn_s_setprio(0);
        // NO end-of-phase barrier (3-buf B / 2-buf As make it redundant)
    }
    __syncthreads();                            // protect Bs reuse as key tile
    // ===== epilogue: segment-max pre-reduced in LDS, then sparse flush =====
    const int dbase = dstS[e0];
    const int drange = dstS[e0 + 63] - dbase + 1;
    unsigned int* tile = (unsigned int*)Bs;      // 16 rows x 256 cols = 16 KB
    if (drange <= 16) {
        uint4 zz = {0u, 0u, 0u, 0u};
#pragma unroll
        for (int i = 0; i < 4; ++i) ((uint4*)tile)[i * 256 + t] = zz;   // zero
        __syncthreads();
#pragma unroll
        for (int mt = 0; mt < 4; ++mt) {
            int base = mt * 16 + (l >> 4) * 4;
            const int4 dd = *(const int4*)(dstS + e0 + base);   // L2-hot
            int r0 = dd.x - dbase, r1 = dd.y - dbase, r2 = dd.z - dbase, r3 = dd.w - dbase;
#pragma unroll
            for (int nt = 0; nt < 4; ++nt) {
                int colb = wnb + nt * 16 + lm;
                f32x4 a = acc[mt][nt];
                float m = a[0];
                if (r1 == r0) m = fmaxf(m, a[1]);
                else { atomicMax(tile + r0 * 256 + colb, fkey(m)); m = a[1]; }
                if (r2 == r1) m = fmaxf(m, a[2]);
                else { atomicMax(tile + r1 * 256 + colb, fkey(m)); m = a[2]; }
                if (r3 == r2) m = fmaxf(m, a[3]);
                else { atomicMax(tile + r2 * 256 + colb, fkey(m)); m = a[3]; }
                atomicMax(tile + r3 * 256 + colb, fkey(m));
            }
        }
        __syncthreads();
        // flush: thread t owns column n0+t across all rows
#pragma unroll 4
        for (int r = 0; r < 16; ++r) {
            if (r < drange) {
                unsigned int kv = tile[r * 256 + t];
                if (kv) {
                    unsigned int* addr = K + (((size_t)(dbase + r)) << 9) + n0 + t;
                    if (r > 0 && r < drange - 1) *addr = kv;   // single writer
                    else atomicMax(addr, kv);                  // boundary row
                }
            }
        }
    } else {
        // fallback (degenerate range): direct run-compressed global flushes
#pragma unroll
        for (int mt = 0; mt < 4; ++mt) {
            int base = mt * 16 + (l >> 4) * 4;
            const int4 dd = *(const int4*)(dstS + e0 + base);
            int d0 = dd.x, d1 = dd.y, d2 = dd.z, d3 = dd.w;
#pragma unroll
            for (int nt = 0; nt < 4; ++nt) {
                int col = n0 + wnb + nt * 16 + lm;
                f32x4 a = acc[mt][nt];
                float m = a[0];
                if (d1 == d0) m = fmaxf(m, a[1]); else { kflush(K, d0, col, m); m = a[1]; }
                if (d2 == d1) m = fmaxf(m, a[2]); else { kflush(K, d1, col, m); m = a[2]; }
                if (d3 == d2) m = fmaxf(m, a[3]); else { kflush(K, d2, col, m); m = a[3]; }
                kflush(K, d3, col, m);
            }
        }
    }
}

// ================= decode keys -> h bf16; re-zero keys for next layer =================
__global__ __launch_bounds__(256) void decode_kernel(
    unsigned int* __restrict__ K, const float* __restrict__ b2,
    short* __restrict__ hb) {
    int idx = blockIdx.x * 256 + threadIdx.x;
    unsigned int k = K[idx];
    K[idx] = 0u;                       // init for next layer's atomicMax
    int c = idx & (HDIM - 1);
    float v = 0.f;
    if (k != 0u) {
        unsigned int b = (k & 0x80000000u) ? (k ^ 0x80000000u) : ~k;
        v = __uint_as_float(b) + b2[c];
    }
    hb[idx] = (short)f2b(fmaxf(v, 0.f));
}

// ================= gather (bf16) =================
__global__ __launch_bounds__(256) void gather_bf16_kernel(
    const short* __restrict__ hb, const int* __restrict__ sel,
    short* __restrict__ hgb) {
    int idx = blockIdx.x * 256 + threadIdx.x;          // 4096 rows x 64 chunks
    int row = idx >> 6, c = idx & 63;
    int b = row >> 9;                                  // SEL = 512
    int s = sel[row];
    ((uint4*)hgb)[idx] = ((const uint4*)(hb + (((size_t)(b * SEQ + s)) << 9)))[c];
}

// ================= MFMA GEMM (FFN), bf16 in, bf16 or fp32 out =================
__global__ __launch_bounds__(256) void ffn_gemm_kernel(
    const short* __restrict__ A, const short* __restrict__ Wt,
    const float* __restrict__ bias, short* __restrict__ Cb,
    float* __restrict__ Cf, int relu) {
    __shared__ short As[128 * 32];
    __shared__ short Bs[128 * 32];
    const int t = threadIdx.x;
    const int m0 = blockIdx.x * 128, n0 = blockIdx.y * 128;
    const int w = t >> 6, l = t & 63;
    const int wm = (w & 1) * 64, wn = (w >> 1) * 64;
    f32x4 acc[4][4] = {};
    for (int kc = 0; kc < HDIM; kc += 32) {
        stage_tile(A + (size_t)m0 * HDIM, kc, As, t);
        stage_tile(Wt + (size_t)n0 * HDIM, kc, Bs, t);
        __syncthreads();
        mfma_tile_bf16(As, Bs, wm, wn, l, acc);
        __syncthreads();
    }
#pragma unroll
    for (int mt = 0; mt < 4; ++mt) {
        int m = m0 + wm + mt * 16 + (l >> 4) * 4;
#pragma unroll
        for (int nt = 0; nt < 4; ++nt) {
            int n = n0 + wn + nt * 16 + (l & 15);
            float bv = bias[n];
#pragma unroll
            for (int r = 0; r < 4; ++r) {
                float v = acc[mt][nt][r] + bv;
                if (relu) v = fmaxf(v, 0.f);
                if (Cf) Cf[(size_t)(m + r) * HDIM + n] = v;
                else    Cb[(size_t)(m + r) * HDIM + n] = (short)f2b(v);
            }
        }
    }
}

extern "C" void kernel_launch(void* const* d_in, const int* in_sizes, int n_in,
                              void* d_out, int out_size, void* d_ws, size_t ws_size,
                              hipStream_t stream) {
    const float* x   = (const float*)d_in[0];
    const int*   ei  = (const int*)d_in[1];
    const int*   sel = (const int*)d_in[2];
    const int*   src = ei;
    const int*   dst = ei + EDGES;
    const float* cw1[3] = {(const float*)d_in[4],  (const float*)d_in[8],  (const float*)d_in[12]};
    const float* cb1[3] = {(const float*)d_in[5],  (const float*)d_in[9],  (const float*)d_in[13]};
    const float* cw2[3] = {(const float*)d_in[6],  (const float*)d_in[10], (const float*)d_in[14]};
    const float* cb2[3] = {(const float*)d_in[7],  (const float*)d_in[11], (const float*)d_in[15]};
    const float* fw1 = (const float*)d_in[16];
    const float* fb1 = (const float*)d_in[17];
    const float* fw2 = (const float*)d_in[18];
    const float* fb2 = (const float*)d_in[19];
    float* out = (float*)d_out;

    const size_t MB = 1024 * 1024;
    char* p = (char*)d_ws;
    unsigned int* keys = (unsigned int*)p;                   // 32 MB
    short* U    = (short*)(p + 32 * MB);                     // 16 MB (fp16)
    short* V    = (short*)(p + 48 * MB);                     // 16 MB (fp16)
    short* hb   = (short*)(p + 64 * MB);                     // 16 MB (bf16)
    short* WdT  = (short*)(p + 80 * MB);                     // 0.5 MB each
    short* w1bT = WdT + 512 * 512;
    short* W2T  = w1bT + 512 * 512;                          // fp16
    short* fw1T = W2T + 512 * 512;
    short* fw2T = fw1T + 512 * 512;
    int*   dstS = (int*)(p + 83 * MB);                       // 1 MB
    int*   srcS = (int*)(p + 84 * MB);                       // 1 MB
    int*   hist = (int*)(p + 85 * MB);                       // 64 KB
    int*   curs = hist + N_NODES;                            // 64 KB
    short* hgb  = (short*)(p + 86 * MB);                     // 4 MB
    short* t1b  = (short*)(p + 90 * MB);                     // 4 MB

    // --- sort edges by dst (edges constant across layers) ---
    (void)hipMemsetAsync(hist, 0, N_NODES * sizeof(int), stream);
    hist_kernel<<<EDGES / 256, 256, 0, stream>>>(dst, hist);
    scan_kernel<<<1, 256, 0, stream>>>(hist, curs);
    scatter_kernel<<<EDGES / 256, 256, 0, stream>>>(dst, src, curs, dstS, srcS);

    cvt_bf16_kernel<<<8192, 256, 0, stream>>>(x, hb);
    tr_kernel<<<dim3(16, 16, 2), dim3(32, 8), 0, stream>>>(fw1, fw2, fw1T, fw2T);
    (void)hipMemsetAsync(keys, 0, 32 * MB, stream);          // layer-0 key init

    for (int l = 0; l < 3; ++l) {
        prep_weights_kernel<<<dim3(16, 16, 3), dim3(32, 8), 0, stream>>>(
            cw1[l], cw2[l], WdT, w1bT, W2T);
        node_gemm_uv_kernel<<<dim3(128, 8), 256, 0, stream>>>(hb, WdT, w1bT, cb1[l], U, V);
        edge_mfma_kernel<<<8192, 256, 0, stream>>>(U, V, W2T, srcS, dstS, keys);
        decode_kernel<<<(N_NODES * HDIM) / 256, 256, 0, stream>>>(keys, cb2[l], hb);
    }

    gather_bf16_kernel<<<(4096 * 64) / 256, 256, 0, stream>>>(hb, sel, hgb);
    ffn_gemm_kernel<<<dim3(32, 4), 256, 0, stream>>>(hgb, fw1T, fb1, t1b, nullptr, 1);
    ffn_gemm_kernel<<<dim3(32, 4), 256, 0, stream>>>(t1b, fw2T, fb2, nullptr, out, 0);
}

// Round 7
// 907.367 us; speedup vs baseline: 1.0839x; 1.0839x over previous
//
#include <hip/hip_runtime.h>
#include <hip/hip_bf16.h>

// UCCAEncoder: 3x EdgeConv(max) + FFN + gather. R16:
//  - REVERT R15 (single-barrier skew: avg 205->242us + 41ms outlier). Back to
//    the proven 2-barrier counted-vmcnt phase structure (R12/R14).
//  - NEW: 64x128 per-wave output tiles. Block = 64 edges x 512 cols, 256 thr,
//    4 waves, acc[4][8] (128 VGPR). Fragment reads per block drop to 75%
//    (A-reads halve: 4 waves share As instead of 8); per-phase compute:read
//    ratio 160:144 cy vs 80:96 -> reads hidden under own-wave MFMA.
//  - vmcnt FIFO resim (8 B-ops + 4 A-ops per thread): steady vmcnt(12),
//    hh=14: vmcnt(8), hh=15: vmcnt(0). Robust to reload/stage reorder: ops
//    younger than B(hh) always = A(4)+B(8)=12.
//  - LDS: As 8KB single + Bs 2x32KB dbuf = 72KB -> 2 blocks/CU.
//  - keeps: LDS key-tile epilogue (16x512 in Bs[0], interior plain stores),
//    sorted edges, XCD swizzle, fused U/V node GEMM, fp16 z path, MFMA FFN.

#define N_NODES 16384
#define EDGES   262144
#define HDIM    512
#define SEQ     2048

typedef __attribute__((ext_vector_type(8))) short short8;
typedef __attribute__((ext_vector_type(8))) _Float16 half8;
typedef __attribute__((ext_vector_type(2))) _Float16 half2v;
typedef __attribute__((ext_vector_type(4))) float f32x4;

__device__ __forceinline__ void gld16(const void* g, void* l) {
    __builtin_amdgcn_global_load_lds(
        (const __attribute__((address_space(1))) void*)g,
        (__attribute__((address_space(3))) void*)l, 16, 0, 0);
}
__device__ __forceinline__ unsigned short f2b(float f) {   // fp32 -> bf16 RNE
    unsigned int x = __float_as_uint(f);
    return (unsigned short)((x + 0x7fffu + ((x >> 16) & 1u)) >> 16);
}
__device__ __forceinline__ unsigned short f2h(float f) {   // fp32 -> fp16 bits
    _Float16 h = (_Float16)f;
    return __builtin_bit_cast(unsigned short, h);
}
// packed fp16: z = max(u+v, 0) (v_pk_add_f16 + v_pk_max_f16)
__device__ __forceinline__ unsigned int zpack_h(unsigned int u, unsigned int v) {
    half2v a = __builtin_bit_cast(half2v, u);
    half2v b = __builtin_bit_cast(half2v, v);
    half2v s = a + b;
    half2v z = {(_Float16)0.f, (_Float16)0.f};
    half2v r = __builtin_elementwise_max(s, z);
    return __builtin_bit_cast(unsigned int, r);
}
// ---- Bk=32 LDS swizzle (node/FFN GEMMs): slot = seg ^ ((row>>1)&3), row stride 64B
__device__ __forceinline__ short8 frag_ld(const short* S, int row, int q) {
    int p = q ^ ((row >> 1) & 3);
    return *(const short8*)(S + row * 32 + p * 8);
}
__device__ __forceinline__ void stage_tile(const short* G, int kc, short* S, int t) {
#pragma unroll
    for (int it = 0; it < 2; ++it) {
        int lin = it * 256 + t;
        int row = lin >> 2, p = lin & 3;
        int q = p ^ ((row >> 1) & 3);
        gld16(G + (size_t)row * HDIM + kc + q * 8, S + lin * 8);
    }
}
__device__ __forceinline__ void mfma_tile_bf16(const short* As, const short* Bs,
                                               int wm, int wn, int l, f32x4 acc[4][4]) {
    short8 a[4], b[4];
#pragma unroll
    for (int mt = 0; mt < 4; ++mt) a[mt] = frag_ld(As, wm + mt * 16 + (l & 15), l >> 4);
#pragma unroll
    for (int nt = 0; nt < 4; ++nt) b[nt] = frag_ld(Bs, wn + nt * 16 + (l & 15), l >> 4);
#pragma unroll
    for (int mt = 0; mt < 4; ++mt)
#pragma unroll
        for (int nt = 0; nt < 4; ++nt)
            acc[mt][nt] = __builtin_amdgcn_mfma_f32_16x16x32_bf16(a[mt], b[nt], acc[mt][nt], 0, 0, 0);
}
// ---- Bk=64 LDS swizzle (edge A tile): row stride 128B = bank wrap ->
//      slot = seg ^ ((row>>1)&7) ^ (row&1); 8 segs of 8 els per row.
__device__ __forceinline__ half8 frag64(const short* S, int row, int q) {
    int p = q ^ ((row >> 1) & 7) ^ (row & 1);
    return *(const half8*)(S + row * 64 + p * 8);
}
// ---- Bk=32 B-chunk staging (edge kernel, 256 thr): 512 rows x 32 els
__device__ __forceinline__ void stageB32n(const short* __restrict__ Wt, int col0,
                                          short* buf, int t) {
#pragma unroll
    for (int it = 0; it < 8; ++it) {
        int lin = it * 256 + t;                // 0..2047
        int row = lin >> 2, s = lin & 3;
        int q = s ^ ((row >> 1) & 3);
        gld16(Wt + (size_t)row * HDIM + col0 + q * 8, buf + lin * 8);
    }
}

// ================= edge sort (counting sort by dst) =================
__global__ __launch_bounds__(256) void hist_kernel(
    const int* __restrict__ dst, int* __restrict__ hist) {
    int idx = blockIdx.x * 256 + threadIdx.x;
    atomicAdd(&hist[dst[idx]], 1);
}
__global__ __launch_bounds__(256) void scan_kernel(
    const int* __restrict__ hist, int* __restrict__ cursor) {
    __shared__ int part[256];
    const int t = threadIdx.x, base = t * 64;
    int sum = 0;
    for (int i = 0; i < 64; ++i) sum += hist[base + i];
    part[t] = sum;
    __syncthreads();
    int run = 0;
    for (int i = 0; i < t; ++i) run += part[i];
    for (int i = 0; i < 64; ++i) {
        int h = hist[base + i];
        cursor[base + i] = run;
        run += h;
    }
}
__global__ __launch_bounds__(256) void scatter_kernel(
    const int* __restrict__ dst, const int* __restrict__ src,
    int* __restrict__ cursor, int* __restrict__ dstS, int* __restrict__ srcS) {
    int idx = blockIdx.x * 256 + threadIdx.x;
    int d = dst[idx];
    int p = atomicAdd(&cursor[d], 1);
    dstS[p] = d;
    srcS[p] = src[idx];
}

// ================= weights / input prep =================
// conv trio -> [n][k]: z=0 Wd=w1a-w1b (bf16), z=1 w1b (bf16), z=2 w2 (fp16)
__global__ __launch_bounds__(256) void prep_weights_kernel(
    const float* __restrict__ w1, const float* __restrict__ w2,
    short* __restrict__ WdT, short* __restrict__ w1bT, short* __restrict__ W2T) {
    __shared__ float tile[32][33];
    const int which = blockIdx.z;
    const int k0 = blockIdx.x * 32, n0 = blockIdx.y * 32;
    const int tx = threadIdx.x, ty = threadIdx.y;
#pragma unroll
    for (int i = 0; i < 4; ++i) {
        int k = k0 + ty + i * 8, n = n0 + tx;
        float v;
        if (which == 0)      v = w1[k * 512 + n] - w1[(k + 512) * 512 + n];
        else if (which == 1) v = w1[(k + 512) * 512 + n];
        else                 v = w2[k * 512 + n];
        tile[ty + i * 8][tx] = v;
    }
    __syncthreads();
    short* out = which == 0 ? WdT : (which == 1 ? w1bT : W2T);
#pragma unroll
    for (int i = 0; i < 4; ++i) {
        int n = n0 + ty + i * 8, k = k0 + tx;
        float v = tile[tx][ty + i * 8];
        out[(size_t)n * 512 + k] = (short)(which == 2 ? f2h(v) : f2b(v));
    }
}
// FFN mats (bf16): z=0 fw1, z=1 fw2
__global__ __launch_bounds__(256) void tr_kernel(
    const float* __restrict__ W1, const float* __restrict__ W2,
    short* __restrict__ T1, short* __restrict__ T2) {
    __shared__ float tile[32][33];
    const float* W = blockIdx.z ? W2 : W1;
    short* T = blockIdx.z ? T2 : T1;
    const int k0 = blockIdx.x * 32, n0 = blockIdx.y * 32;
    const int tx = threadIdx.x, ty = threadIdx.y;
#pragma unroll
    for (int i = 0; i < 4; ++i)
        tile[ty + i * 8][tx] = W[(k0 + ty + i * 8) * 512 + n0 + tx];
    __syncthreads();
#pragma unroll
    for (int i = 0; i < 4; ++i)
        T[(size_t)(n0 + ty + i * 8) * 512 + k0 + tx] = (short)f2b(tile[tx][ty + i * 8]);
}
__global__ __launch_bounds__(256) void cvt_bf16_kernel(
    const float* __restrict__ x, short* __restrict__ xb) {
    int idx = blockIdx.x * 256 + threadIdx.x;
    float4 v = ((const float4*)x)[idx];
    uint2 o;
    o.x = (unsigned int)f2b(v.x) | ((unsigned int)f2b(v.y) << 16);
    o.y = (unsigned int)f2b(v.z) | ((unsigned int)f2b(v.w) << 16);
    ((uint2*)xb)[idx] = o;
}

// ================= fused U/V node GEMM (bf16 in, fp16 out) =================
// grid (128, 8): y<4 -> U = h@WdT^T + b1 ; y>=4 -> V = h@w1bT^T
__global__ __launch_bounds__(256) void node_gemm_uv_kernel(
    const short* __restrict__ A, const short* __restrict__ WdT,
    const short* __restrict__ w1bT, const float* __restrict__ b1,
    short* __restrict__ U, short* __restrict__ V) {
    __shared__ short As[128 * 32];
    __shared__ short Bs[128 * 32];
    const int t = threadIdx.x;
    const int by = blockIdx.y;
    const short* Wt = (by < 4) ? WdT : w1bT;
    short* C = (by < 4) ? U : V;
    const float* bias = (by < 4) ? b1 : nullptr;
    const int m0 = blockIdx.x * 128, n0 = (by & 3) * 128;
    const int w = t >> 6, l = t & 63;
    const int wm = (w & 1) * 64, wn = (w >> 1) * 64;
    f32x4 acc[4][4] = {};
    for (int kc = 0; kc < HDIM; kc += 32) {
        stage_tile(A + (size_t)m0 * HDIM, kc, As, t);
        stage_tile(Wt + (size_t)n0 * HDIM, kc, Bs, t);
        __syncthreads();
        mfma_tile_bf16(As, Bs, wm, wn, l, acc);
        __syncthreads();
    }
#pragma unroll
    for (int mt = 0; mt < 4; ++mt) {
        int m = m0 + wm + mt * 16 + (l >> 4) * 4;
#pragma unroll
        for (int nt = 0; nt < 4; ++nt) {
            int n = n0 + wn + nt * 16 + (l & 15);
            float bv = bias ? bias[n] : 0.f;
#pragma unroll
            for (int r = 0; r < 4; ++r)
                C[(size_t)(m + r) * HDIM + n] = (short)f2h(acc[mt][nt][r] + bv);
        }
    }
}

// ====== edge GEMM (sorted, fp16, 64e x 512c, 4 waves x 64x128, vmcnt) ======
__device__ __forceinline__ unsigned int fkey(float m) {    // monotone fp32->uint
    unsigned int b = __float_as_uint(m);
    return ((int)b < 0) ? ~b : (b | 0x80000000u);
}
__device__ __forceinline__ void kflush(unsigned int* K, int d, int col, float m) {
    atomicMax(K + (((size_t)d) << 9) + col, fkey(m));
}
__global__ __launch_bounds__(256, 2) void edge_mfma_kernel(
    const short* __restrict__ U, const short* __restrict__ V,
    const short* __restrict__ Wt, const int* __restrict__ srcS,
    const int* __restrict__ dstS, unsigned int* __restrict__ K) {
    __shared__ short As[64 * 64];         // 8 KB (z, fp16, full Bk=64, single)
    __shared__ short Bs[2][512 * 32];     // 64 KB (W2^T full width, Bk=32 dbuf)
    // total 72 KB -> 2 blocks/CU
    const int t = threadIdx.x;
    // XCD swizzle: 4096 groups -> contiguous 512-group chunk per XCD
    const int L  = blockIdx.x;                 // 0..4095
    const int g  = (L & 7) * 512 + (L >> 3);   // edge-group
    const int e0 = g * 64;
    const int w = t >> 6, l = t & 63;
    const int wnb = w * 128;                   // 128-col slice of 512
    const int lm = l & 15;
    const int arow = t >> 2, s0 = (t & 3) * 2; // thread covers 32B (segs s0,s0+1)
    const int perm = ((arow >> 1) & 7) ^ (arow & 1);
    const int p0 = s0 ^ perm, p1 = (s0 + 1) ^ perm;
    const int drow = dstS[e0 + arow];          // L2-hot
    const int srow = srcS[e0 + arow];
    const short* up = U + (((size_t)drow) << 9) + s0 * 8;
    const short* vp = V + (((size_t)srow) << 9) + s0 * 8;
    unsigned int* As_u = (unsigned int*)As;
    f32x4 acc[4][8] = {};
    uint4 pu0, pu1, pv0, pv1;
    // prologue: B chunk 0 (8 ops), then A gathers for kc=0 (4 ops)
    stageB32n(Wt, 0, Bs[0], t);
    pu0 = *(const uint4*)(up);
    pu1 = *(const uint4*)(up + 8);
    pv0 = *(const uint4*)(vp);
    pv1 = *(const uint4*)(vp + 8);
    // 16 half-steps; step hh: cols [(hh>>1)*64 + (hh&1)*32, +32) from Bs[hh&1].
    // vm FIFO (B=8, A=4 ops/thread): at explicit wait, ops younger than B(hh)
    // = A(4)+B(hh+1)(8) = 12 in ANY issue order -> vmcnt(12) drains B(hh).
    // hh=14: only B15 younger -> vmcnt(8). hh=15: vmcnt(0). zpack's implicit
    // wait drains only through its A loads (B prefetches stay in flight).
#pragma unroll
    for (int hh = 0; hh < 16; ++hh) {
        const int kc = (hh >> 1) * 64;
        if (hh < 15) {
            const int c1 = ((hh + 1) >> 1) * 64 + ((hh + 1) & 1) * 32;
            stageB32n(Wt, c1, Bs[(hh + 1) & 1], t);
        }
        if ((hh & 1) == 0) {
            // consume A(kc): z = relu(u+v) -> swizzled As (full Bk=64 row)
            uint4 z0, z1;
            z0.x = zpack_h(pu0.x, pv0.x); z0.y = zpack_h(pu0.y, pv0.y);
            z0.z = zpack_h(pu0.z, pv0.z); z0.w = zpack_h(pu0.w, pv0.w);
            z1.x = zpack_h(pu1.x, pv1.x); z1.y = zpack_h(pu1.y, pv1.y);
            z1.z = zpack_h(pu1.z, pv1.z); z1.w = zpack_h(pu1.w, pv1.w);
            *(uint4*)(As_u + arow * 32 + p0 * 4) = z0;
            *(uint4*)(As_u + arow * 32 + p1 * 4) = z1;
            if (hh < 14) {                     // reload SAME regs for kc+64
                pu0 = *(const uint4*)(up + kc + 64);
                pu1 = *(const uint4*)(up + kc + 64 + 8);
                pv0 = *(const uint4*)(vp + kc + 64);
                pv1 = *(const uint4*)(vp + kc + 64 + 8);
            }
        }
        // wait: current B chunk landed (counted, never drains the prefetches)
        if (hh <= 13)      asm volatile("s_waitcnt vmcnt(12) lgkmcnt(0)" ::: "memory");
        else if (hh == 14) asm volatile("s_waitcnt vmcnt(8) lgkmcnt(0)" ::: "memory");
        else               asm volatile("s_waitcnt vmcnt(0) lgkmcnt(0)" ::: "memory");
        __builtin_amdgcn_s_barrier();
        asm volatile("" ::: "memory");          // pin ds_reads below the barrier
        const short* Bb = Bs[hh & 1];
        const int hq = (hh & 1) * 4 + (l >> 4); // A seg index for this K-slice
        __builtin_amdgcn_s_setprio(1);
        half8 b[8];
#pragma unroll
        for (int nt = 0; nt < 8; ++nt) {
            int row = wnb + nt * 16 + lm;
            int p = (l >> 4) ^ ((row >> 1) & 3);
            b[nt] = *(const half8*)(Bb + row * 32 + p * 8);
        }
#pragma unroll
        for (int mt = 0; mt < 4; ++mt) {
            half8 a = frag64(As, mt * 16 + lm, hq);
#pragma unroll
            for (int nt = 0; nt < 8; ++nt)
                acc[mt][nt] = __builtin_amdgcn_mfma_f32_16x16x32_f16(a, b[nt], acc[mt][nt], 0, 0, 0);
        }
        __builtin_amdgcn_s_setprio(0);
        asm volatile("" ::: "memory");          // pin ds_reads above the end barrier
        __builtin_amdgcn_s_barrier();           // buf[hh&1] free for next DMA
    }
    // ===== epilogue: segment-max pre-reduced in LDS, then sparse flush =====
    // 64 sorted edges span <16 distinct dst -> 16x512 key tile in Bs[0] (32KB,
    // dead after final barrier). Interior rows: single writer -> plain store.
    const int dbase = dstS[e0];
    const int drange = dstS[e0 + 63] - dbase + 1;
    unsigned int* tile = (unsigned int*)Bs[0];   // 16 rows x 512 cols = 32 KB
    if (drange <= 16) {
        uint4 zz = {0u, 0u, 0u, 0u};
#pragma unroll
        for (int i = 0; i < 8; ++i) ((uint4*)tile)[i * 256 + t] = zz;  // zero
        __syncthreads();
#pragma unroll
        for (int mt = 0; mt < 4; ++mt) {
            int base = mt * 16 + (l >> 4) * 4;
            const int4 dd = *(const int4*)(dstS + e0 + base);   // L2-hot
            int r0 = dd.x - dbase, r1 = dd.y - dbase, r2 = dd.z - dbase, r3 = dd.w - dbase;
#pragma unroll
            for (int nt = 0; nt < 8; ++nt) {
                int colb = wnb + nt * 16 + lm;
                f32x4 a = acc[mt][nt];
                float m = a[0];
                if (r1 == r0) m = fmaxf(m, a[1]);
                else { atomicMax(tile + r0 * 512 + colb, fkey(m)); m = a[1]; }
                if (r2 == r1) m = fmaxf(m, a[2]);
                else { atomicMax(tile + r1 * 512 + colb, fkey(m)); m = a[2]; }
                if (r3 == r2) m = fmaxf(m, a[3]);
                else { atomicMax(tile + r2 * 512 + colb, fkey(m)); m = a[3]; }
                atomicMax(tile + r3 * 512 + colb, fkey(m));
            }
        }
        __syncthreads();
        // flush: thread t owns columns t and 256+t across all rows
#pragma unroll 4
        for (int r = 0; r < 16; ++r) {
            if (r < drange) {
                unsigned int kv0 = tile[r * 512 + t];
                unsigned int kv1 = tile[r * 512 + 256 + t];
                unsigned int* rowp = K + (((size_t)(dbase + r)) << 9);
                bool interior = (r > 0 && r < drange - 1);
                if (kv0) { if (interior) rowp[t] = kv0; else atomicMax(rowp + t, kv0); }
                if (kv1) { if (interior) rowp[256 + t] = kv1; else atomicMax(rowp + 256 + t, kv1); }
            }
        }
    } else {
        // fallback (degenerate range): direct run-compressed global flushes
#pragma unroll
        for (int mt = 0; mt < 4; ++mt) {
            int base = mt * 16 + (l >> 4) * 4;
            const int4 dd = *(const int4*)(dstS + e0 + base);
            int d0 = dd.x, d1 = dd.y, d2 = dd.z, d3 = dd.w;
#pragma unroll
            for (int nt = 0; nt < 8; ++nt) {
                int col = wnb + nt * 16 + lm;
                f32x4 a = acc[mt][nt];
                float m = a[0];
                if (d1 == d0) m = fmaxf(m, a[1]); else { kflush(K, d0, col, m); m = a[1]; }
                if (d2 == d1) m = fmaxf(m, a[2]); else { kflush(K, d1, col, m); m = a[2]; }
                if (d3 == d2) m = fmaxf(m, a[3]); else { kflush(K, d2, col, m); m = a[3]; }
                kflush(K, d3, col, m);
            }
        }
    }
}

// ================= decode keys -> h bf16; re-zero keys for next layer =================
__global__ __launch_bounds__(256) void decode_kernel(
    unsigned int* __restrict__ K, const float* __restrict__ b2,
    short* __restrict__ hb) {
    int idx = blockIdx.x * 256 + threadIdx.x;
    unsigned int k = K[idx];
    K[idx] = 0u;                       // init for next layer's atomicMax
    int c = idx & (HDIM - 1);
    float v = 0.f;
    if (k != 0u) {
        unsigned int b = (k & 0x80000000u) ? (k ^ 0x80000000u) : ~k;
        v = __uint_as_float(b) + b2[c];
    }
    hb[idx] = (short)f2b(fmaxf(v, 0.f));
}

// ================= gather (bf16) =================
__global__ __launch_bounds__(256) void gather_bf16_kernel(
    const short* __restrict__ hb, const int* __restrict__ sel,
    short* __restrict__ hgb) {
    int idx = blockIdx.x * 256 + threadIdx.x;          // 4096 rows x 64 chunks
    int row = idx >> 6, c = idx & 63;
    int b = row >> 9;                                  // SEL = 512
    int s = sel[row];
    ((uint4*)hgb)[idx] = ((const uint4*)(hb + (((size_t)(b * SEQ + s)) << 9)))[c];
}

// ================= MFMA GEMM (FFN), bf16 in, bf16 or fp32 out =================
__global__ __launch_bounds__(256) void ffn_gemm_kernel(
    const short* __restrict__ A, const short* __restrict__ Wt,
    const float* __restrict__ bias, short* __restrict__ Cb,
    float* __restrict__ Cf, int relu) {
    __shared__ short As[128 * 32];
    __shared__ short Bs[128 * 32];
    const int t = threadIdx.x;
    const int m0 = blockIdx.x * 128, n0 = blockIdx.y * 128;
    const int w = t >> 6, l = t & 63;
    const int wm = (w & 1) * 64, wn = (w >> 1) * 64;
    f32x4 acc[4][4] = {};
    for (int kc = 0; kc < HDIM; kc += 32) {
        stage_tile(A + (size_t)m0 * HDIM, kc, As, t);
        stage_tile(Wt + (size_t)n0 * HDIM, kc, Bs, t);
        __syncthreads();
        mfma_tile_bf16(As, Bs, wm, wn, l, acc);
        __syncthreads();
    }
#pragma unroll
    for (int mt = 0; mt < 4; ++mt) {
        int m = m0 + wm + mt * 16 + (l >> 4) * 4;
#pragma unroll
        for (int nt = 0; nt < 4; ++nt) {
            int n = n0 + wn + nt * 16 + (l & 15);
            float bv = bias[n];
#pragma unroll
            for (int r = 0; r < 4; ++r) {
                float v = acc[mt][nt][r] + bv;
                if (relu) v = fmaxf(v, 0.f);
                if (Cf) Cf[(size_t)(m + r) * HDIM + n] = v;
                else    Cb[(size_t)(m + r) * HDIM + n] = (short)f2b(v);
            }
        }
    }
}

extern "C" void kernel_launch(void* const* d_in, const int* in_sizes, int n_in,
                              void* d_out, int out_size, void* d_ws, size_t ws_size,
                              hipStream_t stream) {
    const float* x   = (const float*)d_in[0];
    const int*   ei  = (const int*)d_in[1];
    const int*   sel = (const int*)d_in[2];
    const int*   src = ei;
    const int*   dst = ei + EDGES;
    const float* cw1[3] = {(const float*)d_in[4],  (const float*)d_in[8],  (const float*)d_in[12]};
    const float* cb1[3] = {(const float*)d_in[5],  (const float*)d_in[9],  (const float*)d_in[13]};
    const float* cw2[3] = {(const float*)d_in[6],  (const float*)d_in[10], (const float*)d_in[14]};
    const float* cb2[3] = {(const float*)d_in[7],  (const float*)d_in[11], (const float*)d_in[15]};
    const float* fw1 = (const float*)d_in[16];
    const float* fb1 = (const float*)d_in[17];
    const float* fw2 = (const float*)d_in[18];
    const float* fb2 = (const float*)d_in[19];
    float* out = (float*)d_out;

    const size_t MB = 1024 * 1024;
    char* p = (char*)d_ws;
    unsigned int* keys = (unsigned int*)p;                   // 32 MB
    short* U    = (short*)(p + 32 * MB);                     // 16 MB (fp16)
    short* V    = (short*)(p + 48 * MB);                     // 16 MB (fp16)
    short* hb   = (short*)(p + 64 * MB);                     // 16 MB (bf16)
    short* WdT  = (short*)(p + 80 * MB);                     // 0.5 MB each
    short* w1bT = WdT + 512 * 512;
    short* W2T  = w1bT + 512 * 512;                          // fp16
    short* fw1T = W2T + 512 * 512;
    short* fw2T = fw1T + 512 * 512;
    int*   dstS = (int*)(p + 83 * MB);                       // 1 MB
    int*   srcS = (int*)(p + 84 * MB);                       // 1 MB
    int*   hist = (int*)(p + 85 * MB);                       // 64 KB
    int*   curs = hist + N_NODES;                            // 64 KB
    short* hgb  = (short*)(p + 86 * MB);                     // 4 MB
    short* t1b  = (short*)(p + 90 * MB);                     // 4 MB

    // --- sort edges by dst (edges constant across layers) ---
    (void)hipMemsetAsync(hist, 0, N_NODES * sizeof(int), stream);
    hist_kernel<<<EDGES / 256, 256, 0, stream>>>(dst, hist);
    scan_kernel<<<1, 256, 0, stream>>>(hist, curs);
    scatter_kernel<<<EDGES / 256, 256, 0, stream>>>(dst, src, curs, dstS, srcS);

    cvt_bf16_kernel<<<8192, 256, 0, stream>>>(x, hb);
    tr_kernel<<<dim3(16, 16, 2), dim3(32, 8), 0, stream>>>(fw1, fw2, fw1T, fw2T);
    (void)hipMemsetAsync(keys, 0, 32 * MB, stream);          // layer-0 key init

    for (int l = 0; l < 3; ++l) {
        prep_weights_kernel<<<dim3(16, 16, 3), dim3(32, 8), 0, stream>>>(
            cw1[l], cw2[l], WdT, w1bT, W2T);
        node_gemm_uv_kernel<<<dim3(128, 8), 256, 0, stream>>>(hb, WdT, w1bT, cb1[l], U, V);
        edge_mfma_kernel<<<4096, 256, 0, stream>>>(U, V, W2T, srcS, dstS, keys);
        decode_kernel<<<(N_NODES * HDIM) / 256, 256, 0, stream>>>(keys, cb2[l], hb);
    }

    gather_bf16_kernel<<<(4096 * 64) / 256, 256, 0, stream>>>(hb, sel, hgb);
    ffn_gemm_kernel<<<dim3(32, 4), 256, 0, stream>>>(hgb, fw1T, fb1, t1b, nullptr, 1);
    ffn_gemm_kernel<<<dim3(32, 4), 256, 0, stream>>>(t1b, fw2T, fb2, nullptr, out, 0);
}

// Round 8
// 845.222 us; speedup vs baseline: 1.1636x; 1.0735x over previous
//
#include <hip/hip_runtime.h>
#include <hip/hip_bf16.h>

// UCCAEncoder: 3x EdgeConv(max) + FFN + gather. R17:
//  - edge kernel: REVERT to R12 exact (best measured: 203.4us). R13-R16
//    perturbations (occupancy, merge, barrier-elision, big tiles) all flat or
//    worse -> ~203us is this structure's practical floor (MFMA floor 66us,
//    LDS ~55%, multi-resource equilibrium).
//  - NEW (non-edge, ~255us previously untouched):
//    (a) node_gemm_uv merged: one block stages A(h) ONCE and computes both
//        U (x WdT) and V (x w1bT) 128x128 tiles. 3 stages/step vs 4, A L2
//        traffic halved. accU+accV = 128 regs, __launch_bounds__(256,2).
//    (b) ffn_gemm retiled 64x128 -> grid 256 blocks (was 128 = half GPU idle);
//        gather FUSED into ffn1 A-stage via sel-indirected per-lane DMA src.
//        gather kernel + hgb round-trip removed.
//    (c) decode vectorized (uint2/thread).

#define N_NODES 16384
#define EDGES   262144
#define HDIM    512
#define SEQ     2048

typedef __attribute__((ext_vector_type(8))) short short8;
typedef __attribute__((ext_vector_type(8))) _Float16 half8;
typedef __attribute__((ext_vector_type(2))) _Float16 half2v;
typedef __attribute__((ext_vector_type(4))) float f32x4;

__device__ __forceinline__ void gld16(const void* g, void* l) {
    __builtin_amdgcn_global_load_lds(
        (const __attribute__((address_space(1))) void*)g,
        (__attribute__((address_space(3))) void*)l, 16, 0, 0);
}
__device__ __forceinline__ unsigned short f2b(float f) {   // fp32 -> bf16 RNE
    unsigned int x = __float_as_uint(f);
    return (unsigned short)((x + 0x7fffu + ((x >> 16) & 1u)) >> 16);
}
__device__ __forceinline__ unsigned short f2h(float f) {   // fp32 -> fp16 bits
    _Float16 h = (_Float16)f;
    return __builtin_bit_cast(unsigned short, h);
}
// packed fp16: z = max(u+v, 0) (v_pk_add_f16 + v_pk_max_f16)
__device__ __forceinline__ unsigned int zpack_h(unsigned int u, unsigned int v) {
    half2v a = __builtin_bit_cast(half2v, u);
    half2v b = __builtin_bit_cast(half2v, v);
    half2v s = a + b;
    half2v z = {(_Float16)0.f, (_Float16)0.f};
    half2v r = __builtin_elementwise_max(s, z);
    return __builtin_bit_cast(unsigned int, r);
}
// ---- Bk=32 LDS swizzle (node/FFN GEMMs): slot = seg ^ ((row>>1)&3), row stride 64B
__device__ __forceinline__ short8 frag_ld(const short* S, int row, int q) {
    int p = q ^ ((row >> 1) & 3);
    return *(const short8*)(S + row * 32 + p * 8);
}
__device__ __forceinline__ void stage_tile(const short* G, int kc, short* S, int t) {
#pragma unroll
    for (int it = 0; it < 2; ++it) {
        int lin = it * 256 + t;
        int row = lin >> 2, p = lin & 3;
        int q = p ^ ((row >> 1) & 3);
        gld16(G + (size_t)row * HDIM + kc + q * 8, S + lin * 8);
    }
}
// ---- Bk=64 LDS swizzle (edge A tile): row stride 128B = bank wrap ->
//      slot = seg ^ ((row>>1)&7) ^ (row&1); 8 segs of 8 els per row.
__device__ __forceinline__ half8 frag64(const short* S, int row, int q) {
    int p = q ^ ((row >> 1) & 7) ^ (row & 1);
    return *(const half8*)(S + row * 64 + p * 8);
}
// ---- Bk=32 B-chunk staging (edge kernel): 256 rows x 32 els, dbuf
__device__ __forceinline__ void stageB32(const short* __restrict__ Wt, int n0, int col0,
                                         short* buf, int t) {
#pragma unroll
    for (int it = 0; it < 4; ++it) {
        int lin = it * 256 + t;
        int row = lin >> 2, s = lin & 3;
        int q = s ^ ((row >> 1) & 3);
        gld16(Wt + (size_t)(n0 + row) * HDIM + col0 + q * 8, buf + lin * 8);
    }
}

// ================= edge sort (counting sort by dst) =================
__global__ __launch_bounds__(256) void hist_kernel(
    const int* __restrict__ dst, int* __restrict__ hist) {
    int idx = blockIdx.x * 256 + threadIdx.x;
    atomicAdd(&hist[dst[idx]], 1);
}
__global__ __launch_bounds__(256) void scan_kernel(
    const int* __restrict__ hist, int* __restrict__ cursor) {
    __shared__ int part[256];
    const int t = threadIdx.x, base = t * 64;
    int sum = 0;
    for (int i = 0; i < 64; ++i) sum += hist[base + i];
    part[t] = sum;
    __syncthreads();
    int run = 0;
    for (int i = 0; i < t; ++i) run += part[i];
    for (int i = 0; i < 64; ++i) {
        int h = hist[base + i];
        cursor[base + i] = run;
        run += h;
    }
}
__global__ __launch_bounds__(256) void scatter_kernel(
    const int* __restrict__ dst, const int* __restrict__ src,
    int* __restrict__ cursor, int* __restrict__ dstS, int* __restrict__ srcS) {
    int idx = blockIdx.x * 256 + threadIdx.x;
    int d = dst[idx];
    int p = atomicAdd(&cursor[d], 1);
    dstS[p] = d;
    srcS[p] = src[idx];
}

// ================= weights / input prep =================
// conv trio -> [n][k]: z=0 Wd=w1a-w1b (bf16), z=1 w1b (bf16), z=2 w2 (fp16)
__global__ __launch_bounds__(256) void prep_weights_kernel(
    const float* __restrict__ w1, const float* __restrict__ w2,
    short* __restrict__ WdT, short* __restrict__ w1bT, short* __restrict__ W2T) {
    __shared__ float tile[32][33];
    const int which = blockIdx.z;
    const int k0 = blockIdx.x * 32, n0 = blockIdx.y * 32;
    const int tx = threadIdx.x, ty = threadIdx.y;
#pragma unroll
    for (int i = 0; i < 4; ++i) {
        int k = k0 + ty + i * 8, n = n0 + tx;
        float v;
        if (which == 0)      v = w1[k * 512 + n] - w1[(k + 512) * 512 + n];
        else if (which == 1) v = w1[(k + 512) * 512 + n];
        else                 v = w2[k * 512 + n];
        tile[ty + i * 8][tx] = v;
    }
    __syncthreads();
    short* out = which == 0 ? WdT : (which == 1 ? w1bT : W2T);
#pragma unroll
    for (int i = 0; i < 4; ++i) {
        int n = n0 + ty + i * 8, k = k0 + tx;
        float v = tile[tx][ty + i * 8];
        out[(size_t)n * 512 + k] = (short)(which == 2 ? f2h(v) : f2b(v));
    }
}
// FFN mats (bf16): z=0 fw1, z=1 fw2
__global__ __launch_bounds__(256) void tr_kernel(
    const float* __restrict__ W1, const float* __restrict__ W2,
    short* __restrict__ T1, short* __restrict__ T2) {
    __shared__ float tile[32][33];
    const float* W = blockIdx.z ? W2 : W1;
    short* T = blockIdx.z ? T2 : T1;
    const int k0 = blockIdx.x * 32, n0 = blockIdx.y * 32;
    const int tx = threadIdx.x, ty = threadIdx.y;
#pragma unroll
    for (int i = 0; i < 4; ++i)
        tile[ty + i * 8][tx] = W[(k0 + ty + i * 8) * 512 + n0 + tx];
    __syncthreads();
#pragma unroll
    for (int i = 0; i < 4; ++i)
        T[(size_t)(n0 + ty + i * 8) * 512 + k0 + tx] = (short)f2b(tile[tx][ty + i * 8]);
}
__global__ __launch_bounds__(256) void cvt_bf16_kernel(
    const float* __restrict__ x, short* __restrict__ xb) {
    int idx = blockIdx.x * 256 + threadIdx.x;
    float4 v = ((const float4*)x)[idx];
    uint2 o;
    o.x = (unsigned int)f2b(v.x) | ((unsigned int)f2b(v.y) << 16);
    o.y = (unsigned int)f2b(v.z) | ((unsigned int)f2b(v.w) << 16);
    ((uint2*)xb)[idx] = o;
}

// ========== fused U/V node GEMM, MERGED: stage A once, both B mats ==========
// grid (128, 4): block computes U[128x128] AND V[128x128] for same (m0,n0).
__global__ __launch_bounds__(256, 2) void node_gemm_uv_kernel(
    const short* __restrict__ A, const short* __restrict__ WdT,
    const short* __restrict__ w1bT, const float* __restrict__ b1,
    short* __restrict__ U, short* __restrict__ V) {
    __shared__ short As[128 * 32];
    __shared__ short Bu[128 * 32];
    __shared__ short Bv[128 * 32];
    const int t = threadIdx.x;
    const int m0 = blockIdx.x * 128, n0 = blockIdx.y * 128;
    const int w = t >> 6, l = t & 63;
    const int wm = (w & 1) * 64, wn = (w >> 1) * 64;
    f32x4 aU[4][4] = {}, aV[4][4] = {};
    for (int kc = 0; kc < HDIM; kc += 32) {
        stage_tile(A + (size_t)m0 * HDIM, kc, As, t);
        stage_tile(WdT + (size_t)n0 * HDIM, kc, Bu, t);
        stage_tile(w1bT + (size_t)n0 * HDIM, kc, Bv, t);
        __syncthreads();
        short8 a[4], bu[4], bv[4];
#pragma unroll
        for (int mt = 0; mt < 4; ++mt) a[mt] = frag_ld(As, wm + mt * 16 + (l & 15), l >> 4);
#pragma unroll
        for (int nt = 0; nt < 4; ++nt) {
            bu[nt] = frag_ld(Bu, wn + nt * 16 + (l & 15), l >> 4);
            bv[nt] = frag_ld(Bv, wn + nt * 16 + (l & 15), l >> 4);
        }
#pragma unroll
        for (int mt = 0; mt < 4; ++mt)
#pragma unroll
            for (int nt = 0; nt < 4; ++nt) {
                aU[mt][nt] = __builtin_amdgcn_mfma_f32_16x16x32_bf16(a[mt], bu[nt], aU[mt][nt], 0, 0, 0);
                aV[mt][nt] = __builtin_amdgcn_mfma_f32_16x16x32_bf16(a[mt], bv[nt], aV[mt][nt], 0, 0, 0);
            }
        __syncthreads();
    }
#pragma unroll
    for (int mt = 0; mt < 4; ++mt) {
        int m = m0 + wm + mt * 16 + (l >> 4) * 4;
#pragma unroll
        for (int nt = 0; nt < 4; ++nt) {
            int n = n0 + wn + nt * 16 + (l & 15);
            float bv = b1[n];
#pragma unroll
            for (int r = 0; r < 4; ++r) {
                U[(size_t)(m + r) * HDIM + n] = (short)f2h(aU[mt][nt][r] + bv);
                V[(size_t)(m + r) * HDIM + n] = (short)f2h(aV[mt][nt][r]);
            }
        }
    }
}

// ====== edge GEMM (R12 exact: sorted, fp16, 64e x 256n, counted-vmcnt) ======
__device__ __forceinline__ unsigned int fkey(float m) {    // monotone fp32->uint
    unsigned int b = __float_as_uint(m);
    return ((int)b < 0) ? ~b : (b | 0x80000000u);
}
__device__ __forceinline__ void kflush(unsigned int* K, int d, int col, float m) {
    atomicMax(K + (((size_t)d) << 9) + col, fkey(m));
}
__global__ __launch_bounds__(256, 3) void edge_mfma_kernel(
    const short* __restrict__ U, const short* __restrict__ V,
    const short* __restrict__ Wt, const int* __restrict__ srcS,
    const int* __restrict__ dstS, unsigned int* __restrict__ K) {
    __shared__ short As[64 * 64];         // 8 KB (z, fp16, full Bk=64, single buf)
    __shared__ short Bs[2][256 * 32];     // 32 KB (W2^T, fp16, Bk=32 dbuf)
    __shared__ int sdst[64], ssrc[64];
    const int t = threadIdx.x;
    // XCD swizzle: L%8 = XCD; the 2 n-halves of edge-group g are 8 apart (same XCD).
    const int L  = blockIdx.x;                 // 0..8191
    const int g  = (L >> 4) * 8 + (L & 7);     // edge-group 0..4095 (64 edges each)
    const int nh = (L >> 3) & 1;               // n-half
    const int e0 = g * 64, n0 = nh * 256;
    if (t < 64) { sdst[t] = dstS[e0 + t]; ssrc[t] = srcS[e0 + t]; }
    __syncthreads();
    const int w = t >> 6, l = t & 63;
    const int wnb = w * 64;                    // 64-col slice
    const int lm = l & 15;
    const int arow = t >> 2, s0 = (t & 3) * 2; // thread covers 32B (segs s0,s0+1)
    const int perm = ((arow >> 1) & 7) ^ (arow & 1);
    const int p0 = s0 ^ perm, p1 = (s0 + 1) ^ perm;
    const short* up = U + (((size_t)sdst[arow]) << 9) + s0 * 8;
    const short* vp = V + (((size_t)ssrc[arow]) << 9) + s0 * 8;
    unsigned int* As_u = (unsigned int*)As;
    f32x4 acc[4][4] = {};
    uint4 pu0, pu1, pv0, pv1, nu0, nu1, nv0, nv1;
    // prologue: B chunk 0, then A gathers for kc=0 (issue order matters for counts)
    stageB32(Wt, n0, 0, Bs[0], t);
    pu0 = *(const uint4*)(up);
    pu1 = *(const uint4*)(up + 8);
    pv0 = *(const uint4*)(vp);
    pv1 = *(const uint4*)(vp + 8);
    // 16 half-steps; per step hh: chunk cols [ (hh>>1)*64 + (hh&1)*32, +32 )
#pragma unroll
    for (int hh = 0; hh < 16; ++hh) {
        const int kc = (hh >> 1) * 64;
        // issue next B chunk into the other buffer (stays in flight across barriers)
        if (hh < 15) {
            const int c1 = ((hh + 1) >> 1) * 64 + ((hh + 1) & 1) * 32;
            stageB32(Wt, n0, c1, Bs[(hh + 1) & 1], t);
        }
        if ((hh & 1) == 0) {
            if (hh < 14) {                      // A gathers for kc+64, 2 phases ahead
                nu0 = *(const uint4*)(up + kc + 64);
                nu1 = *(const uint4*)(up + kc + 64 + 8);
                nv0 = *(const uint4*)(vp + kc + 64);
                nv1 = *(const uint4*)(vp + kc + 64 + 8);
            }
            // consume A(kc) regs: z = relu(u+v) -> swizzled As (full Bk=64 row)
            uint4 z0, z1;
            z0.x = zpack_h(pu0.x, pv0.x); z0.y = zpack_h(pu0.y, pv0.y);
            z0.z = zpack_h(pu0.z, pv0.z); z0.w = zpack_h(pu0.w, pv0.w);
            z1.x = zpack_h(pu1.x, pv1.x); z1.y = zpack_h(pu1.y, pv1.y);
            z1.z = zpack_h(pu1.z, pv1.z); z1.w = zpack_h(pu1.w, pv1.w);
            *(uint4*)(As_u + arow * 32 + p0 * 4) = z0;
            *(uint4*)(As_u + arow * 32 + p1 * 4) = z1;
        }
        // wait: current B chunk landed (counted, never drains the prefetches)
        if (hh < 14)       asm volatile("s_waitcnt vmcnt(8) lgkmcnt(0)" ::: "memory");
        else if (hh == 14) asm volatile("s_waitcnt vmcnt(4) lgkmcnt(0)" ::: "memory");
        else               asm volatile("s_waitcnt vmcnt(0) lgkmcnt(0)" ::: "memory");
        __builtin_amdgcn_s_barrier();
        asm volatile("" ::: "memory");          // pin ds_reads below the barrier
        const short* Bb = Bs[hh & 1];
        const int hq = (hh & 1) * 4 + (l >> 4); // A seg index for this K-slice
        __builtin_amdgcn_s_setprio(1);
        half8 b[4];
#pragma unroll
        for (int nt = 0; nt < 4; ++nt) {
            int row = wnb + nt * 16 + lm;
            int p = (l >> 4) ^ ((row >> 1) & 3);
            b[nt] = *(const half8*)(Bb + row * 32 + p * 8);
        }
#pragma unroll
        for (int mt = 0; mt < 4; ++mt) {
            half8 a = frag64(As, mt * 16 + lm, hq);
#pragma unroll
            for (int nt = 0; nt < 4; ++nt)
                acc[mt][nt] = __builtin_amdgcn_mfma_f32_16x16x32_f16(a, b[nt], acc[mt][nt], 0, 0, 0);
        }
        __builtin_amdgcn_s_setprio(0);
        if ((hh & 1) == 0 && hh < 14) { pu0 = nu0; pu1 = nu1; pv0 = nv0; pv1 = nv1; }
        asm volatile("" ::: "memory");          // pin ds_reads above the end barrier
        __builtin_amdgcn_s_barrier();           // buf[hh&1] free for next DMA
    }
    // ===== epilogue: segment-max pre-reduced in LDS, then sparse global flush =====
    const int dbase = sdst[0];
    const int drange = sdst[63] - dbase + 1;
    unsigned int* tile = (unsigned int*)Bs[1];   // 16 rows x 256 cols = 16 KB
    if (drange <= 16) {
#pragma unroll
        for (int i = 0; i < 16; ++i) tile[i * 256 + t] = 0u;   // zero tile
        __syncthreads();
#pragma unroll
        for (int mt = 0; mt < 4; ++mt) {
            int base = mt * 16 + (l >> 4) * 4;
            int d0 = sdst[base], d1 = sdst[base + 1], d2 = sdst[base + 2], d3 = sdst[base + 3];
            int r0 = d0 - dbase, r1 = d1 - dbase, r2 = d2 - dbase, r3 = d3 - dbase;
#pragma unroll
            for (int nt = 0; nt < 4; ++nt) {
                int colb = wnb + nt * 16 + lm;
                f32x4 a = acc[mt][nt];
                float m = a[0];
                if (d1 == d0) m = fmaxf(m, a[1]);
                else { atomicMax(tile + r0 * 256 + colb, fkey(m)); m = a[1]; }
                if (d2 == d1) m = fmaxf(m, a[2]);
                else { atomicMax(tile + r1 * 256 + colb, fkey(m)); m = a[2]; }
                if (d3 == d2) m = fmaxf(m, a[3]);
                else { atomicMax(tile + r2 * 256 + colb, fkey(m)); m = a[3]; }
                atomicMax(tile + r3 * 256 + colb, fkey(m));
            }
        }
        __syncthreads();
        // flush non-empty rows: thread t owns column n0+t across all rows
#pragma unroll 4
        for (int r = 0; r < 16; ++r) {
            if (r < drange) {
                unsigned int kv = tile[r * 256 + t];
                if (kv) atomicMax(K + (((size_t)(dbase + r)) << 9) + n0 + t, kv);
            }
        }
    } else {
        // fallback (degenerate range): direct run-compressed global flushes
#pragma unroll
        for (int mt = 0; mt < 4; ++mt) {
            int base = mt * 16 + (l >> 4) * 4;
            int d0 = sdst[base], d1 = sdst[base + 1], d2 = sdst[base + 2], d3 = sdst[base + 3];
#pragma unroll
            for (int nt = 0; nt < 4; ++nt) {
                int col = n0 + wnb + nt * 16 + lm;
                f32x4 a = acc[mt][nt];
                float m = a[0];
                if (d1 == d0) m = fmaxf(m, a[1]); else { kflush(K, d0, col, m); m = a[1]; }
                if (d2 == d1) m = fmaxf(m, a[2]); else { kflush(K, d1, col, m); m = a[2]; }
                if (d3 == d2) m = fmaxf(m, a[3]); else { kflush(K, d2, col, m); m = a[3]; }
                kflush(K, d3, col, m);
            }
        }
    }
}

// ======= decode keys -> h bf16 (x2 vectorized); re-zero keys for next layer =======
__global__ __launch_bounds__(256) void decode_kernel(
    unsigned int* __restrict__ K, const float* __restrict__ b2,
    short* __restrict__ hb) {
    int idx = blockIdx.x * 256 + threadIdx.x;          // 2 keys per thread
    uint2 k = ((uint2*)K)[idx];
    uint2 zz = {0u, 0u};
    ((uint2*)K)[idx] = zz;                             // init for next layer
    int c = (idx << 1) & (HDIM - 1);
    float v0 = 0.f, v1 = 0.f;
    if (k.x != 0u) {
        unsigned int b = (k.x & 0x80000000u) ? (k.x ^ 0x80000000u) : ~k.x;
        v0 = __uint_as_float(b) + b2[c];
    }
    if (k.y != 0u) {
        unsigned int b = (k.y & 0x80000000u) ? (k.y ^ 0x80000000u) : ~k.y;
        v1 = __uint_as_float(b) + b2[c + 1];
    }
    unsigned int o = (unsigned int)f2b(fmaxf(v0, 0.f))
                   | ((unsigned int)f2b(fmaxf(v1, 0.f)) << 16);
    ((unsigned int*)hb)[idx] = o;
}

// ========= MFMA GEMM (FFN), 64x128 tiles, optional sel-gather on A =========
// grid (64, 4), 256 thr, 4 waves 2x2, wave tile 32x64, acc[2][4].
__global__ __launch_bounds__(256) void ffn_gemm_kernel(
    const short* __restrict__ A, const int* __restrict__ sel,
    const short* __restrict__ Wt, const float* __restrict__ bias,
    short* __restrict__ Cb, float* __restrict__ Cf, int relu) {
    __shared__ short As[64 * 32];      // 4 KB
    __shared__ short Bs[128 * 32];     // 8 KB
    const int t = threadIdx.x;
    const int m0 = blockIdx.x * 64, n0 = blockIdx.y * 128;
    const int w = t >> 6, l = t & 63;
    const int wm = (w & 1) * 32, wn = (w >> 1) * 64;
    // A-stage address (one 16B seg per thread per step): row = t>>2, slot p = t&3
    const int srow = t >> 2, sp = t & 3;
    const int sq = sp ^ ((srow >> 1) & 3);
    const short* ap;
    if (sel) {                                   // fused gather: row -> hb row
        int gr = m0 + srow;                      // 0..4095
        ap = A + (((size_t)((gr >> 9) * SEQ + sel[gr])) << 9);
    } else {
        ap = A + (size_t)(m0 + srow) * HDIM;
    }
    f32x4 acc[2][4] = {};
    for (int kc = 0; kc < HDIM; kc += 32) {
        gld16(ap + kc + sq * 8, As + t * 8);
        stage_tile(Wt + (size_t)n0 * HDIM, kc, Bs, t);
        __syncthreads();
        short8 a[2], b[4];
#pragma unroll
        for (int mt = 0; mt < 2; ++mt) a[mt] = frag_ld(As, wm + mt * 16 + (l & 15), l >> 4);
#pragma unroll
        for (int nt = 0; nt < 4; ++nt) b[nt] = frag_ld(Bs, wn + nt * 16 + (l & 15), l >> 4);
#pragma unroll
        for (int mt = 0; mt < 2; ++mt)
#pragma unroll
            for (int nt = 0; nt < 4; ++nt)
                acc[mt][nt] = __builtin_amdgcn_mfma_f32_16x16x32_bf16(a[mt], b[nt], acc[mt][nt], 0, 0, 0);
        __syncthreads();
    }
#pragma unroll
    for (int mt = 0; mt < 2; ++mt) {
        int m = m0 + wm + mt * 16 + (l >> 4) * 4;
#pragma unroll
        for (int nt = 0; nt < 4; ++nt) {
            int n = n0 + wn + nt * 16 + (l & 15);
            float bv = bias[n];
#pragma unroll
            for (int r = 0; r < 4; ++r) {
                float v = acc[mt][nt][r] + bv;
                if (relu) v = fmaxf(v, 0.f);
                if (Cf) Cf[(size_t)(m + r) * HDIM + n] = v;
                else    Cb[(size_t)(m + r) * HDIM + n] = (short)f2b(v);
            }
        }
    }
}

extern "C" void kernel_launch(void* const* d_in, const int* in_sizes, int n_in,
                              void* d_out, int out_size, void* d_ws, size_t ws_size,
                              hipStream_t stream) {
    const float* x   = (const float*)d_in[0];
    const int*   ei  = (const int*)d_in[1];
    const int*   sel = (const int*)d_in[2];
    const int*   src = ei;
    const int*   dst = ei + EDGES;
    const float* cw1[3] = {(const float*)d_in[4],  (const float*)d_in[8],  (const float*)d_in[12]};
    const float* cb1[3] = {(const float*)d_in[5],  (const float*)d_in[9],  (const float*)d_in[13]};
    const float* cw2[3] = {(const float*)d_in[6],  (const float*)d_in[10], (const float*)d_in[14]};
    const float* cb2[3] = {(const float*)d_in[7],  (const float*)d_in[11], (const float*)d_in[15]};
    const float* fw1 = (const float*)d_in[16];
    const float* fb1 = (const float*)d_in[17];
    const float* fw2 = (const float*)d_in[18];
    const float* fb2 = (const float*)d_in[19];
    float* out = (float*)d_out;

    const size_t MB = 1024 * 1024;
    char* p = (char*)d_ws;
    unsigned int* keys = (unsigned int*)p;                   // 32 MB
    short* U    = (short*)(p + 32 * MB);                     // 16 MB (fp16)
    short* V    = (short*)(p + 48 * MB);                     // 16 MB (fp16)
    short* hb   = (short*)(p + 64 * MB);                     // 16 MB (bf16)
    short* WdT  = (short*)(p + 80 * MB);                     // 0.5 MB each
    short* w1bT = WdT + 512 * 512;
    short* W2T  = w1bT + 512 * 512;                          // fp16
    short* fw1T = W2T + 512 * 512;
    short* fw2T = fw1T + 512 * 512;
    int*   dstS = (int*)(p + 83 * MB);                       // 1 MB
    int*   srcS = (int*)(p + 84 * MB);                       // 1 MB
    int*   hist = (int*)(p + 85 * MB);                       // 64 KB
    int*   curs = hist + N_NODES;                            // 64 KB
    short* t1b  = (short*)(p + 90 * MB);                     // 4 MB

    // --- sort edges by dst (edges constant across layers) ---
    (void)hipMemsetAsync(hist, 0, N_NODES * sizeof(int), stream);
    hist_kernel<<<EDGES / 256, 256, 0, stream>>>(dst, hist);
    scan_kernel<<<1, 256, 0, stream>>>(hist, curs);
    scatter_kernel<<<EDGES / 256, 256, 0, stream>>>(dst, src, curs, dstS, srcS);

    cvt_bf16_kernel<<<8192, 256, 0, stream>>>(x, hb);
    tr_kernel<<<dim3(16, 16, 2), dim3(32, 8), 0, stream>>>(fw1, fw2, fw1T, fw2T);
    (void)hipMemsetAsync(keys, 0, 32 * MB, stream);          // layer-0 key init

    for (int l = 0; l < 3; ++l) {
        prep_weights_kernel<<<dim3(16, 16, 3), dim3(32, 8), 0, stream>>>(
            cw1[l], cw2[l], WdT, w1bT, W2T);
        node_gemm_uv_kernel<<<dim3(128, 4), 256, 0, stream>>>(hb, WdT, w1bT, cb1[l], U, V);
        edge_mfma_kernel<<<8192, 256, 0, stream>>>(U, V, W2T, srcS, dstS, keys);
        decode_kernel<<<(N_NODES * HDIM / 2) / 256, 256, 0, stream>>>(keys, cb2[l], hb);
    }

    // FFN: gather fused into GEMM1's A-stage via sel indirection
    ffn_gemm_kernel<<<dim3(64, 4), 256, 0, stream>>>(hb, sel, fw1T, fb1, t1b, nullptr, 1);
    ffn_gemm_kernel<<<dim3(64, 4), 256, 0, stream>>>(t1b, nullptr, fw2T, fb2, nullptr, out, 0);
}

// Round 9
// 828.475 us; speedup vs baseline: 1.1872x; 1.0202x over previous
//
#include <hip/hip_runtime.h>
#include <hip/hip_bf16.h>

// UCCAEncoder: 3x EdgeConv(max) + FFN + gather. R18:
//  - edge kernel: unchanged (R12-exact, 203us floor; 31ms rocprof outlier was
//    a cold-clock replay artifact, appears for any structure, pytest unaffected).
//  - node_gemm_uv: counted-vmcnt double-buffer pipeline (proven in edge R11):
//    dbuf As/Bu/Bv (48KB), issue step hh+1's 6 DMAs then s_waitcnt vmcnt(6)
//    (drains exactly step hh; tail vmcnt(0)). Kills the per-step vmcnt(0)
//    drain the naive stage loop had (16x ~300cy exposed L2 latency).
//  - prep_weights batched: one grid.z=9 launch for all 3 layers before the
//    loop (per-layer weight buffers); layer loop is now node->edge->decode.
//  - keeps R17: merged-UV node GEMM, ffn 64x128 retile + fused sel-gather,
//    decode x2 vectorized, LDS key-tile edge epilogue, sorted edges.

#define N_NODES 16384
#define EDGES   262144
#define HDIM    512
#define SEQ     2048

typedef __attribute__((ext_vector_type(8))) short short8;
typedef __attribute__((ext_vector_type(8))) _Float16 half8;
typedef __attribute__((ext_vector_type(2))) _Float16 half2v;
typedef __attribute__((ext_vector_type(4))) float f32x4;

__device__ __forceinline__ void gld16(const void* g, void* l) {
    __builtin_amdgcn_global_load_lds(
        (const __attribute__((address_space(1))) void*)g,
        (__attribute__((address_space(3))) void*)l, 16, 0, 0);
}
__device__ __forceinline__ unsigned short f2b(float f) {   // fp32 -> bf16 RNE
    unsigned int x = __float_as_uint(f);
    return (unsigned short)((x + 0x7fffu + ((x >> 16) & 1u)) >> 16);
}
__device__ __forceinline__ unsigned short f2h(float f) {   // fp32 -> fp16 bits
    _Float16 h = (_Float16)f;
    return __builtin_bit_cast(unsigned short, h);
}
// packed fp16: z = max(u+v, 0) (v_pk_add_f16 + v_pk_max_f16)
__device__ __forceinline__ unsigned int zpack_h(unsigned int u, unsigned int v) {
    half2v a = __builtin_bit_cast(half2v, u);
    half2v b = __builtin_bit_cast(half2v, v);
    half2v s = a + b;
    half2v z = {(_Float16)0.f, (_Float16)0.f};
    half2v r = __builtin_elementwise_max(s, z);
    return __builtin_bit_cast(unsigned int, r);
}
// ---- Bk=32 LDS swizzle (node/FFN GEMMs): slot = seg ^ ((row>>1)&3), row stride 64B
__device__ __forceinline__ short8 frag_ld(const short* S, int row, int q) {
    int p = q ^ ((row >> 1) & 3);
    return *(const short8*)(S + row * 32 + p * 8);
}
__device__ __forceinline__ void stage_tile(const short* G, int kc, short* S, int t) {
#pragma unroll
    for (int it = 0; it < 2; ++it) {
        int lin = it * 256 + t;
        int row = lin >> 2, p = lin & 3;
        int q = p ^ ((row >> 1) & 3);
        gld16(G + (size_t)row * HDIM + kc + q * 8, S + lin * 8);
    }
}
// ---- Bk=64 LDS swizzle (edge A tile): row stride 128B = bank wrap ->
//      slot = seg ^ ((row>>1)&7) ^ (row&1); 8 segs of 8 els per row.
__device__ __forceinline__ half8 frag64(const short* S, int row, int q) {
    int p = q ^ ((row >> 1) & 7) ^ (row & 1);
    return *(const half8*)(S + row * 64 + p * 8);
}
// ---- Bk=32 B-chunk staging (edge kernel): 256 rows x 32 els, dbuf
__device__ __forceinline__ void stageB32(const short* __restrict__ Wt, int n0, int col0,
                                         short* buf, int t) {
#pragma unroll
    for (int it = 0; it < 4; ++it) {
        int lin = it * 256 + t;
        int row = lin >> 2, s = lin & 3;
        int q = s ^ ((row >> 1) & 3);
        gld16(Wt + (size_t)(n0 + row) * HDIM + col0 + q * 8, buf + lin * 8);
    }
}

// ================= edge sort (counting sort by dst) =================
__global__ __launch_bounds__(256) void hist_kernel(
    const int* __restrict__ dst, int* __restrict__ hist) {
    int idx = blockIdx.x * 256 + threadIdx.x;
    atomicAdd(&hist[dst[idx]], 1);
}
__global__ __launch_bounds__(256) void scan_kernel(
    const int* __restrict__ hist, int* __restrict__ cursor) {
    __shared__ int part[256];
    const int t = threadIdx.x, base = t * 64;
    int sum = 0;
    for (int i = 0; i < 64; ++i) sum += hist[base + i];
    part[t] = sum;
    __syncthreads();
    int run = 0;
    for (int i = 0; i < t; ++i) run += part[i];
    for (int i = 0; i < 64; ++i) {
        int h = hist[base + i];
        cursor[base + i] = run;
        run += h;
    }
}
__global__ __launch_bounds__(256) void scatter_kernel(
    const int* __restrict__ dst, const int* __restrict__ src,
    int* __restrict__ cursor, int* __restrict__ dstS, int* __restrict__ srcS) {
    int idx = blockIdx.x * 256 + threadIdx.x;
    int d = dst[idx];
    int p = atomicAdd(&cursor[d], 1);
    dstS[p] = d;
    srcS[p] = src[idx];
}

// ================= weights / input prep =================
// ALL conv layers batched: grid z = 9 (layer = z/3, which = z%3).
// out layout per layer: [Wd | w1b | W2] each 512x512 shorts.
__global__ __launch_bounds__(256) void prep_weights_all_kernel(
    const float* __restrict__ w1_0, const float* __restrict__ w2_0,
    const float* __restrict__ w1_1, const float* __restrict__ w2_1,
    const float* __restrict__ w1_2, const float* __restrict__ w2_2,
    short* __restrict__ outbase) {
    __shared__ float tile[32][33];
    const int z = blockIdx.z;
    const int layer = z / 3, which = z % 3;
    const float* w1 = layer == 0 ? w1_0 : (layer == 1 ? w1_1 : w1_2);
    const float* w2 = layer == 0 ? w2_0 : (layer == 1 ? w2_1 : w2_2);
    const int k0 = blockIdx.x * 32, n0 = blockIdx.y * 32;
    const int tx = threadIdx.x, ty = threadIdx.y;
#pragma unroll
    for (int i = 0; i < 4; ++i) {
        int k = k0 + ty + i * 8, n = n0 + tx;
        float v;
        if (which == 0)      v = w1[k * 512 + n] - w1[(k + 512) * 512 + n];
        else if (which == 1) v = w1[(k + 512) * 512 + n];
        else                 v = w2[k * 512 + n];
        tile[ty + i * 8][tx] = v;
    }
    __syncthreads();
    short* out = outbase + (size_t)(layer * 3 + which) * 512 * 512;
#pragma unroll
    for (int i = 0; i < 4; ++i) {
        int n = n0 + ty + i * 8, k = k0 + tx;
        float v = tile[tx][ty + i * 8];
        out[(size_t)n * 512 + k] = (short)(which == 2 ? f2h(v) : f2b(v));
    }
}
// FFN mats (bf16): z=0 fw1, z=1 fw2
__global__ __launch_bounds__(256) void tr_kernel(
    const float* __restrict__ W1, const float* __restrict__ W2,
    short* __restrict__ T1, short* __restrict__ T2) {
    __shared__ float tile[32][33];
    const float* W = blockIdx.z ? W2 : W1;
    short* T = blockIdx.z ? T2 : T1;
    const int k0 = blockIdx.x * 32, n0 = blockIdx.y * 32;
    const int tx = threadIdx.x, ty = threadIdx.y;
#pragma unroll
    for (int i = 0; i < 4; ++i)
        tile[ty + i * 8][tx] = W[(k0 + ty + i * 8) * 512 + n0 + tx];
    __syncthreads();
#pragma unroll
    for (int i = 0; i < 4; ++i)
        T[(size_t)(n0 + ty + i * 8) * 512 + k0 + tx] = (short)f2b(tile[tx][ty + i * 8]);
}
__global__ __launch_bounds__(256) void cvt_bf16_kernel(
    const float* __restrict__ x, short* __restrict__ xb) {
    int idx = blockIdx.x * 256 + threadIdx.x;
    float4 v = ((const float4*)x)[idx];
    uint2 o;
    o.x = (unsigned int)f2b(v.x) | ((unsigned int)f2b(v.y) << 16);
    o.y = (unsigned int)f2b(v.z) | ((unsigned int)f2b(v.w) << 16);
    ((uint2*)xb)[idx] = o;
}

// ========== fused U/V node GEMM, merged + counted-vmcnt dbuf pipeline ==========
// grid (128, 4): block computes U[128x128] AND V[128x128] for same (m0,n0).
// Per step: issue next step's 6 DMAs, wait vmcnt(6) (drains current step),
// barrier, MFMA, barrier. No vmcnt(0) drain until the tail.
__global__ __launch_bounds__(256, 2) void node_gemm_uv_kernel(
    const short* __restrict__ A, const short* __restrict__ WdT,
    const short* __restrict__ w1bT, const float* __restrict__ b1,
    short* __restrict__ U, short* __restrict__ V) {
    __shared__ short As[2][128 * 32];
    __shared__ short Bu[2][128 * 32];
    __shared__ short Bv[2][128 * 32];   // 48 KB total
    const int t = threadIdx.x;
    const int m0 = blockIdx.x * 128, n0 = blockIdx.y * 128;
    const int w = t >> 6, l = t & 63;
    const int wm = (w & 1) * 64, wn = (w >> 1) * 64;
    const short* Ag = A + (size_t)m0 * HDIM;
    const short* Ug = WdT + (size_t)n0 * HDIM;
    const short* Vg = w1bT + (size_t)n0 * HDIM;
    f32x4 aU[4][4] = {}, aV[4][4] = {};
    // prologue: stage step 0 (6 DMA ops/thread)
    stage_tile(Ag, 0, As[0], t);
    stage_tile(Ug, 0, Bu[0], t);
    stage_tile(Vg, 0, Bv[0], t);
#pragma unroll
    for (int hh = 0; hh < 16; ++hh) {
        if (hh < 15) {
            const int kc1 = (hh + 1) * 32;
            stage_tile(Ag, kc1, As[(hh + 1) & 1], t);
            stage_tile(Ug, kc1, Bu[(hh + 1) & 1], t);
            stage_tile(Vg, kc1, Bv[(hh + 1) & 1], t);
            asm volatile("s_waitcnt vmcnt(6)" ::: "memory");
        } else {
            asm volatile("s_waitcnt vmcnt(0)" ::: "memory");
        }
        __builtin_amdgcn_s_barrier();
        asm volatile("" ::: "memory");      // pin ds_reads below the barrier
        const short* Ab = As[hh & 1];
        const short* Bub = Bu[hh & 1];
        const short* Bvb = Bv[hh & 1];
        short8 a[4], bu[4], bv[4];
#pragma unroll
        for (int mt = 0; mt < 4; ++mt) a[mt] = frag_ld(Ab, wm + mt * 16 + (l & 15), l >> 4);
#pragma unroll
        for (int nt = 0; nt < 4; ++nt) {
            bu[nt] = frag_ld(Bub, wn + nt * 16 + (l & 15), l >> 4);
            bv[nt] = frag_ld(Bvb, wn + nt * 16 + (l & 15), l >> 4);
        }
#pragma unroll
        for (int mt = 0; mt < 4; ++mt)
#pragma unroll
            for (int nt = 0; nt < 4; ++nt) {
                aU[mt][nt] = __builtin_amdgcn_mfma_f32_16x16x32_bf16(a[mt], bu[nt], aU[mt][nt], 0, 0, 0);
                aV[mt][nt] = __builtin_amdgcn_mfma_f32_16x16x32_bf16(a[mt], bv[nt], aV[mt][nt], 0, 0, 0);
            }
        asm volatile("" ::: "memory");      // pin ds_reads above the end barrier
        __builtin_amdgcn_s_barrier();       // buf[hh&1] free for next DMA
    }
#pragma unroll
    for (int mt = 0; mt < 4; ++mt) {
        int m = m0 + wm + mt * 16 + (l >> 4) * 4;
#pragma unroll
        for (int nt = 0; nt < 4; ++nt) {
            int n = n0 + wn + nt * 16 + (l & 15);
            float bv = b1[n];
#pragma unroll
            for (int r = 0; r < 4; ++r) {
                U[(size_t)(m + r) * HDIM + n] = (short)f2h(aU[mt][nt][r] + bv);
                V[(size_t)(m + r) * HDIM + n] = (short)f2h(aV[mt][nt][r]);
            }
        }
    }
}

// ====== edge GEMM (R12 exact: sorted, fp16, 64e x 256n, counted-vmcnt) ======
__device__ __forceinline__ unsigned int fkey(float m) {    // monotone fp32->uint
    unsigned int b = __float_as_uint(m);
    return ((int)b < 0) ? ~b : (b | 0x80000000u);
}
__device__ __forceinline__ void kflush(unsigned int* K, int d, int col, float m) {
    atomicMax(K + (((size_t)d) << 9) + col, fkey(m));
}
__global__ __launch_bounds__(256, 3) void edge_mfma_kernel(
    const short* __restrict__ U, const short* __restrict__ V,
    const short* __restrict__ Wt, const int* __restrict__ srcS,
    const int* __restrict__ dstS, unsigned int* __restrict__ K) {
    __shared__ short As[64 * 64];         // 8 KB (z, fp16, full Bk=64, single buf)
    __shared__ short Bs[2][256 * 32];     // 32 KB (W2^T, fp16, Bk=32 dbuf)
    __shared__ int sdst[64], ssrc[64];
    const int t = threadIdx.x;
    // XCD swizzle: L%8 = XCD; the 2 n-halves of edge-group g are 8 apart (same XCD).
    const int L  = blockIdx.x;                 // 0..8191
    const int g  = (L >> 4) * 8 + (L & 7);     // edge-group 0..4095 (64 edges each)
    const int nh = (L >> 3) & 1;               // n-half
    const int e0 = g * 64, n0 = nh * 256;
    if (t < 64) { sdst[t] = dstS[e0 + t]; ssrc[t] = srcS[e0 + t]; }
    __syncthreads();
    const int w = t >> 6, l = t & 63;
    const int wnb = w * 64;                    // 64-col slice
    const int lm = l & 15;
    const int arow = t >> 2, s0 = (t & 3) * 2; // thread covers 32B (segs s0,s0+1)
    const int perm = ((arow >> 1) & 7) ^ (arow & 1);
    const int p0 = s0 ^ perm, p1 = (s0 + 1) ^ perm;
    const short* up = U + (((size_t)sdst[arow]) << 9) + s0 * 8;
    const short* vp = V + (((size_t)ssrc[arow]) << 9) + s0 * 8;
    unsigned int* As_u = (unsigned int*)As;
    f32x4 acc[4][4] = {};
    uint4 pu0, pu1, pv0, pv1, nu0, nu1, nv0, nv1;
    // prologue: B chunk 0, then A gathers for kc=0 (issue order matters for counts)
    stageB32(Wt, n0, 0, Bs[0], t);
    pu0 = *(const uint4*)(up);
    pu1 = *(const uint4*)(up + 8);
    pv0 = *(const uint4*)(vp);
    pv1 = *(const uint4*)(vp + 8);
    // 16 half-steps; per step hh: chunk cols [ (hh>>1)*64 + (hh&1)*32, +32 )
#pragma unroll
    for (int hh = 0; hh < 16; ++hh) {
        const int kc = (hh >> 1) * 64;
        // issue next B chunk into the other buffer (stays in flight across barriers)
        if (hh < 15) {
            const int c1 = ((hh + 1) >> 1) * 64 + ((hh + 1) & 1) * 32;
            stageB32(Wt, n0, c1, Bs[(hh + 1) & 1], t);
        }
        if ((hh & 1) == 0) {
            if (hh < 14) {                      // A gathers for kc+64, 2 phases ahead
                nu0 = *(const uint4*)(up + kc + 64);
                nu1 = *(const uint4*)(up + kc + 64 + 8);
                nv0 = *(const uint4*)(vp + kc + 64);
                nv1 = *(const uint4*)(vp + kc + 64 + 8);
            }
            // consume A(kc) regs: z = relu(u+v) -> swizzled As (full Bk=64 row)
            uint4 z0, z1;
            z0.x = zpack_h(pu0.x, pv0.x); z0.y = zpack_h(pu0.y, pv0.y);
            z0.z = zpack_h(pu0.z, pv0.z); z0.w = zpack_h(pu0.w, pv0.w);
            z1.x = zpack_h(pu1.x, pv1.x); z1.y = zpack_h(pu1.y, pv1.y);
            z1.z = zpack_h(pu1.z, pv1.z); z1.w = zpack_h(pu1.w, pv1.w);
            *(uint4*)(As_u + arow * 32 + p0 * 4) = z0;
            *(uint4*)(As_u + arow * 32 + p1 * 4) = z1;
        }
        // wait: current B chunk landed (counted, never drains the prefetches)
        if (hh < 14)       asm volatile("s_waitcnt vmcnt(8) lgkmcnt(0)" ::: "memory");
        else if (hh == 14) asm volatile("s_waitcnt vmcnt(4) lgkmcnt(0)" ::: "memory");
        else               asm volatile("s_waitcnt vmcnt(0) lgkmcnt(0)" ::: "memory");
        __builtin_amdgcn_s_barrier();
        asm volatile("" ::: "memory");          // pin ds_reads below the barrier
        const short* Bb = Bs[hh & 1];
        const int hq = (hh & 1) * 4 + (l >> 4); // A seg index for this K-slice
        __builtin_amdgcn_s_setprio(1);
        half8 b[4];
#pragma unroll
        for (int nt = 0; nt < 4; ++nt) {
            int row = wnb + nt * 16 + lm;
            int p = (l >> 4) ^ ((row >> 1) & 3);
            b[nt] = *(const half8*)(Bb + row * 32 + p * 8);
        }
#pragma unroll
        for (int mt = 0; mt < 4; ++mt) {
            half8 a = frag64(As, mt * 16 + lm, hq);
#pragma unroll
            for (int nt = 0; nt < 4; ++nt)
                acc[mt][nt] = __builtin_amdgcn_mfma_f32_16x16x32_f16(a, b[nt], acc[mt][nt], 0, 0, 0);
        }
        __builtin_amdgcn_s_setprio(0);
        if ((hh & 1) == 0 && hh < 14) { pu0 = nu0; pu1 = nu1; pv0 = nv0; pv1 = nv1; }
        asm volatile("" ::: "memory");          // pin ds_reads above the end barrier
        __builtin_amdgcn_s_barrier();           // buf[hh&1] free for next DMA
    }
    // ===== epilogue: segment-max pre-reduced in LDS, then sparse global flush =====
    const int dbase = sdst[0];
    const int drange = sdst[63] - dbase + 1;
    unsigned int* tile = (unsigned int*)Bs[1];   // 16 rows x 256 cols = 16 KB
    if (drange <= 16) {
#pragma unroll
        for (int i = 0; i < 16; ++i) tile[i * 256 + t] = 0u;   // zero tile
        __syncthreads();
#pragma unroll
        for (int mt = 0; mt < 4; ++mt) {
            int base = mt * 16 + (l >> 4) * 4;
            int d0 = sdst[base], d1 = sdst[base + 1], d2 = sdst[base + 2], d3 = sdst[base + 3];
            int r0 = d0 - dbase, r1 = d1 - dbase, r2 = d2 - dbase, r3 = d3 - dbase;
#pragma unroll
            for (int nt = 0; nt < 4; ++nt) {
                int colb = wnb + nt * 16 + lm;
                f32x4 a = acc[mt][nt];
                float m = a[0];
                if (d1 == d0) m = fmaxf(m, a[1]);
                else { atomicMax(tile + r0 * 256 + colb, fkey(m)); m = a[1]; }
                if (d2 == d1) m = fmaxf(m, a[2]);
                else { atomicMax(tile + r1 * 256 + colb, fkey(m)); m = a[2]; }
                if (d3 == d2) m = fmaxf(m, a[3]);
                else { atomicMax(tile + r2 * 256 + colb, fkey(m)); m = a[3]; }
                atomicMax(tile + r3 * 256 + colb, fkey(m));
            }
        }
        __syncthreads();
        // flush non-empty rows: thread t owns column n0+t across all rows
#pragma unroll 4
        for (int r = 0; r < 16; ++r) {
            if (r < drange) {
                unsigned int kv = tile[r * 256 + t];
                if (kv) atomicMax(K + (((size_t)(dbase + r)) << 9) + n0 + t, kv);
            }
        }
    } else {
        // fallback (degenerate range): direct run-compressed global flushes
#pragma unroll
        for (int mt = 0; mt < 4; ++mt) {
            int base = mt * 16 + (l >> 4) * 4;
            int d0 = sdst[base], d1 = sdst[base + 1], d2 = sdst[base + 2], d3 = sdst[base + 3];
#pragma unroll
            for (int nt = 0; nt < 4; ++nt) {
                int col = n0 + wnb + nt * 16 + lm;
                f32x4 a = acc[mt][nt];
                float m = a[0];
                if (d1 == d0) m = fmaxf(m, a[1]); else { kflush(K, d0, col, m); m = a[1]; }
                if (d2 == d1) m = fmaxf(m, a[2]); else { kflush(K, d1, col, m); m = a[2]; }
                if (d3 == d2) m = fmaxf(m, a[3]); else { kflush(K, d2, col, m); m = a[3]; }
                kflush(K, d3, col, m);
            }
        }
    }
}

// ======= decode keys -> h bf16 (x2 vectorized); re-zero keys for next layer =======
__global__ __launch_bounds__(256) void decode_kernel(
    unsigned int* __restrict__ K, const float* __restrict__ b2,
    short* __restrict__ hb) {
    int idx = blockIdx.x * 256 + threadIdx.x;          // 2 keys per thread
    uint2 k = ((uint2*)K)[idx];
    uint2 zz = {0u, 0u};
    ((uint2*)K)[idx] = zz;                             // init for next layer
    int c = (idx << 1) & (HDIM - 1);
    float v0 = 0.f, v1 = 0.f;
    if (k.x != 0u) {
        unsigned int b = (k.x & 0x80000000u) ? (k.x ^ 0x80000000u) : ~k.x;
        v0 = __uint_as_float(b) + b2[c];
    }
    if (k.y != 0u) {
        unsigned int b = (k.y & 0x80000000u) ? (k.y ^ 0x80000000u) : ~k.y;
        v1 = __uint_as_float(b) + b2[c + 1];
    }
    unsigned int o = (unsigned int)f2b(fmaxf(v0, 0.f))
                   | ((unsigned int)f2b(fmaxf(v1, 0.f)) << 16);
    ((unsigned int*)hb)[idx] = o;
}

// ========= MFMA GEMM (FFN), 64x128 tiles, optional sel-gather on A =========
// grid (64, 4), 256 thr, 4 waves 2x2, wave tile 32x64, acc[2][4].
__global__ __launch_bounds__(256) void ffn_gemm_kernel(
    const short* __restrict__ A, const int* __restrict__ sel,
    const short* __restrict__ Wt, const float* __restrict__ bias,
    short* __restrict__ Cb, float* __restrict__ Cf, int relu) {
    __shared__ short As[64 * 32];      // 4 KB
    __shared__ short Bs[128 * 32];     // 8 KB
    const int t = threadIdx.x;
    const int m0 = blockIdx.x * 64, n0 = blockIdx.y * 128;
    const int w = t >> 6, l = t & 63;
    const int wm = (w & 1) * 32, wn = (w >> 1) * 64;
    // A-stage address (one 16B seg per thread per step): row = t>>2, slot p = t&3
    const int srow = t >> 2, sp = t & 3;
    const int sq = sp ^ ((srow >> 1) & 3);
    const short* ap;
    if (sel) {                                   // fused gather: row -> hb row
        int gr = m0 + srow;                      // 0..4095
        ap = A + (((size_t)((gr >> 9) * SEQ + sel[gr])) << 9);
    } else {
        ap = A + (size_t)(m0 + srow) * HDIM;
    }
    f32x4 acc[2][4] = {};
    for (int kc = 0; kc < HDIM; kc += 32) {
        gld16(ap + kc + sq * 8, As + t * 8);
        stage_tile(Wt + (size_t)n0 * HDIM, kc, Bs, t);
        __syncthreads();
        short8 a[2], b[4];
#pragma unroll
        for (int mt = 0; mt < 2; ++mt) a[mt] = frag_ld(As, wm + mt * 16 + (l & 15), l >> 4);
#pragma unroll
        for (int nt = 0; nt < 4; ++nt) b[nt] = frag_ld(Bs, wn + nt * 16 + (l & 15), l >> 4);
#pragma unroll
        for (int mt = 0; mt < 2; ++mt)
#pragma unroll
            for (int nt = 0; nt < 4; ++nt)
                acc[mt][nt] = __builtin_amdgcn_mfma_f32_16x16x32_bf16(a[mt], b[nt], acc[mt][nt], 0, 0, 0);
        __syncthreads();
    }
#pragma unroll
    for (int mt = 0; mt < 2; ++mt) {
        int m = m0 + wm + mt * 16 + (l >> 4) * 4;
#pragma unroll
        for (int nt = 0; nt < 4; ++nt) {
            int n = n0 + wn + nt * 16 + (l & 15);
            float bv = bias[n];
#pragma unroll
            for (int r = 0; r < 4; ++r) {
                float v = acc[mt][nt][r] + bv;
                if (relu) v = fmaxf(v, 0.f);
                if (Cf) Cf[(size_t)(m + r) * HDIM + n] = v;
                else    Cb[(size_t)(m + r) * HDIM + n] = (short)f2b(v);
            }
        }
    }
}

extern "C" void kernel_launch(void* const* d_in, const int* in_sizes, int n_in,
                              void* d_out, int out_size, void* d_ws, size_t ws_size,
                              hipStream_t stream) {
    const float* x   = (const float*)d_in[0];
    const int*   ei  = (const int*)d_in[1];
    const int*   sel = (const int*)d_in[2];
    const int*   src = ei;
    const int*   dst = ei + EDGES;
    const float* cw1[3] = {(const float*)d_in[4],  (const float*)d_in[8],  (const float*)d_in[12]};
    const float* cb1[3] = {(const float*)d_in[5],  (const float*)d_in[9],  (const float*)d_in[13]};
    const float* cw2[3] = {(const float*)d_in[6],  (const float*)d_in[10], (const float*)d_in[14]};
    const float* cb2[3] = {(const float*)d_in[7],  (const float*)d_in[11], (const float*)d_in[15]};
    const float* fw1 = (const float*)d_in[16];
    const float* fb1 = (const float*)d_in[17];
    const float* fw2 = (const float*)d_in[18];
    const float* fb2 = (const float*)d_in[19];
    float* out = (float*)d_out;

    const size_t MB = 1024 * 1024;
    char* p = (char*)d_ws;
    unsigned int* keys = (unsigned int*)p;                   // 32 MB
    short* U    = (short*)(p + 32 * MB);                     // 16 MB (fp16)
    short* V    = (short*)(p + 48 * MB);                     // 16 MB (fp16)
    short* hb   = (short*)(p + 64 * MB);                     // 16 MB (bf16)
    short* Wall = (short*)(p + 80 * MB);                     // 9 x 0.5 MB conv mats
    short* fw1T = Wall + 9 * 512 * 512;                      // FFN mats
    short* fw2T = fw1T + 512 * 512;
    int*   dstS = (int*)(p + 86 * MB);                       // 1 MB
    int*   srcS = (int*)(p + 87 * MB);                       // 1 MB
    int*   hist = (int*)(p + 88 * MB);                       // 64 KB
    int*   curs = hist + N_NODES;                            // 64 KB
    short* t1b  = (short*)(p + 89 * MB);                     // 4 MB

    // --- sort edges by dst (edges constant across layers) ---
    (void)hipMemsetAsync(hist, 0, N_NODES * sizeof(int), stream);
    hist_kernel<<<EDGES / 256, 256, 0, stream>>>(dst, hist);
    scan_kernel<<<1, 256, 0, stream>>>(hist, curs);
    scatter_kernel<<<EDGES / 256, 256, 0, stream>>>(dst, src, curs, dstS, srcS);

    cvt_bf16_kernel<<<8192, 256, 0, stream>>>(x, hb);
    tr_kernel<<<dim3(16, 16, 2), dim3(32, 8), 0, stream>>>(fw1, fw2, fw1T, fw2T);
    prep_weights_all_kernel<<<dim3(16, 16, 9), dim3(32, 8), 0, stream>>>(
        cw1[0], cw2[0], cw1[1], cw2[1], cw1[2], cw2[2], Wall);
    (void)hipMemsetAsync(keys, 0, 32 * MB, stream);          // layer-0 key init

    for (int l = 0; l < 3; ++l) {
        short* WdT  = Wall + (size_t)(l * 3 + 0) * 512 * 512;
        short* w1bT = Wall + (size_t)(l * 3 + 1) * 512 * 512;
        short* W2T  = Wall + (size_t)(l * 3 + 2) * 512 * 512;
        node_gemm_uv_kernel<<<dim3(128, 4), 256, 0, stream>>>(hb, WdT, w1bT, cb1[l], U, V);
        edge_mfma_kernel<<<8192, 256, 0, stream>>>(U, V, W2T, srcS, dstS, keys);
        decode_kernel<<<(N_NODES * HDIM / 2) / 256, 256, 0, stream>>>(keys, cb2[l], hb);
    }

    // FFN: gather fused into GEMM1's A-stage via sel indirection
    ffn_gemm_kernel<<<dim3(64, 4), 256, 0, stream>>>(hb, sel, fw1T, fb1, t1b, nullptr, 1);
    ffn_gemm_kernel<<<dim3(64, 4), 256, 0, stream>>>(t1b, nullptr, fw2T, fb2, nullptr, out, 0);
}